// Round 9
// baseline (263.841 us; speedup 1.0000x reference)
//
#include <hip/hip_runtime.h>
#include <cstdint>
#include <math.h>

#define EPS_BN 1e-5f
#define SLOPE 0.01f
#define C14 6.103515625e-5f     // 2^-14 combine factor
#define SC14 16384.0f           // 2^14 residual scale
#define HMIN 6.103515625e-5f    // fp16 min normal

typedef __attribute__((ext_vector_type(8))) _Float16 half8;
typedef __attribute__((ext_vector_type(8))) short short8;
typedef __attribute__((ext_vector_type(16))) float f32x16;
typedef __attribute__((ext_vector_type(4))) float f32x4;

// 2-way fp16 split: v = h + 2^-14 * l, |v-h-2^-14 l| <= 2^-24|v|
__device__ __forceinline__ void split16(float v, unsigned short& uh,
                                        unsigned short& ul) {
    _Float16 h = (_Float16)v;
    if (fabsf(v) < HMIN) h = (_Float16)0.0f;   // keep h out of subnormal range
    float rem = v - (float)h;
    _Float16 l = (_Float16)(rem * SC14);
    uh = __builtin_bit_cast(unsigned short, h);
    ul = __builtin_bit_cast(unsigned short, l);
}

typedef const __attribute__((address_space(1))) unsigned int* gas_ptr;
typedef __attribute__((address_space(3))) unsigned int* las_ptr;
__device__ __forceinline__ void glds16(const void* g, void* l) {
    __builtin_amdgcn_global_load_lds((gas_ptr)g, (las_ptr)l, 16, 0, 0);
}

// ---------- weight prep, ALL layers: w[O][I][3] fp32 -> fp16-split slots ----
__global__ __launch_bounds__(256)
void wprep_all(const float* __restrict__ w1, short* __restrict__ o1,
               const float* __restrict__ w2, short* __restrict__ o2,
               const float* __restrict__ w3, short* __restrict__ o3,
               const float* __restrict__ w4, short* __restrict__ o4)
{
    const float* w; short* wbuf; int CIN, COUT;
    switch (blockIdx.y) {
        case 0: w = w1; wbuf = o1; CIN = 256; COUT = 256; break;
        case 1: w = w2; wbuf = o2; CIN = 256; COUT = 512; break;
        case 2: w = w3; wbuf = o3; CIN = 512; COUT = 512; break;
        default: w = w4; wbuf = o4; CIN = 512; COUT = 128; break;
    }
    int KST = CIN / 16, OB = COUT / 128;
    int total = KST * OB * 1536;
    for (int sid = blockIdx.x * 256 + threadIdx.x; sid < total;
         sid += gridDim.x * 256) {
        int slot = sid % 1536;
        int kb = sid / 1536;
        int ob = kb % OB, ks = kb / OB;
        int m = slot & 31, hi = (slot >> 5) & 1, mf = (slot >> 6) & 3;
        int ts = slot >> 8;                      // 0..5
        int t = ts >> 1, s = ts & 1;
        int oc = ob * 128 + mf * 32 + m;
        int ib = ks * 16 + hi * 8;
        short8 r;
        #pragma unroll
        for (int j = 0; j < 8; ++j) {
            float v = w[((size_t)oc * CIN + ib + j) * 3 + t];
            unsigned short uh, ul;
            split16(v, uh, ul);
            r[j] = (short)(s == 0 ? uh : ul);
        }
        *(short8*)(wbuf + (size_t)sid * 8) = r;
    }
}

// ---------- BN affine prep (all layers) + argmin-buffer init ----------
__global__ __launch_bounds__(256)
void bnprep_init(
    const float* __restrict__ g1, const float* __restrict__ be1,
    const float* __restrict__ m1, const float* __restrict__ v1,
    const float* __restrict__ b1, float* __restrict__ sc1, float* __restrict__ off1,
    const float* __restrict__ g2, const float* __restrict__ be2,
    const float* __restrict__ m2, const float* __restrict__ v2,
    const float* __restrict__ b2, float* __restrict__ sc2, float* __restrict__ off2,
    const float* __restrict__ g3, const float* __restrict__ be3,
    const float* __restrict__ m3, const float* __restrict__ v3,
    const float* __restrict__ b3, float* __restrict__ sc3, float* __restrict__ off3,
    const float* __restrict__ g4, const float* __restrict__ be4,
    const float* __restrict__ m4, const float* __restrict__ v4,
    const float* __restrict__ b4, float* __restrict__ sc4, float* __restrict__ off4,
    unsigned long long* __restrict__ mp)
{
    int bid = blockIdx.x;
    if (bid >= 6) {
        mp[(bid - 6) * 256 + threadIdx.x] = ~0ULL;
        return;
    }
    const float *g, *be, *m, *v, *bias;
    float *sc, *off;
    int c;
    if (bid == 0) {
        g = g1; be = be1; m = m1; v = v1; bias = b1; sc = sc1; off = off1;
        c = threadIdx.x;
    } else if (bid <= 2) {
        g = g2; be = be2; m = m2; v = v2; bias = b2; sc = sc2; off = off2;
        c = (bid - 1) * 256 + threadIdx.x;
    } else if (bid <= 4) {
        g = g3; be = be3; m = m3; v = v3; bias = b3; sc = sc3; off = off3;
        c = (bid - 3) * 256 + threadIdx.x;
    } else {
        g = g4; be = be4; m = m4; v = v4; bias = b4; sc = sc4; off = off4;
        c = threadIdx.x;
        if (c >= 128) return;
    }
    float s = g[c] / sqrtf(v[c] + EPS_BN);
    sc[c] = s;
    off[c] = (bias[c] - m[c]) * s + be[c];
}

// ---------- x split: fp32 x[32][256][2048] -> 2 fp16 planes, parity slots ------
__global__ __launch_bounds__(256)
void xsplit(const float* __restrict__ x, short* __restrict__ xpl)
{
    const size_t PL = (size_t)32 * 32 * 2 * 1025 * 8;
    int l = blockIdx.x * 256 + threadIdx.x;
    int g = blockIdx.y, b = blockIdx.z;
    float v[8];
    #pragma unroll
    for (int j = 0; j < 8; ++j)
        v[j] = x[((size_t)b * 256 + g * 8 + j) * 2048 + l];
    int arr = l & 1;
    int slot = arr ? (l + 1) / 2 : l / 2 + 1;
    size_t base = ((((size_t)b * 32 + g) * 2 + arr) * 1025 + slot) * 8;
    short8 rh, rl;
    #pragma unroll
    for (int j = 0; j < 8; ++j) {
        unsigned short uh, ul;
        split16(v[j], uh, ul);
        rh[j] = (short)uh; rl[j] = (short)ul;
    }
    *(short8*)(xpl + base) = rh;
    *(short8*)(xpl + PL + base) = rl;
    if (l == 0) {
        short8 z;
        #pragma unroll
        for (int j = 0; j < 8; ++j) z[j] = 0;
        for (int sg = 0; sg < 2; ++sg)
            for (int a2 = 0; a2 < 2; ++a2)
                *(short8*)(xpl + sg * PL +
                           ((((size_t)b * 32 + g) * 2 + a2) * 1025) * 8) = z;
    }
}

// ---------- paired-OC conv (stride 2): 256 oc x TILE pos, 512 thr / 8 waves ----
// Waves 0-3 own oc-half 0, waves 4-7 own oc-half 1; X staged ONCE for both
// halves (halves X-plane traffic vs 128-oc blocks). EPI: 0 = E/O planes,
// 1 = A planes. TILE=128 -> wave 64x64 (2x2 frags); TILE=64 -> wave 64x32 (2x1).
template<int CIN, int COUT, int LIN, int TILE, int EPI>
__global__ __launch_bounds__(512, 1)
void conv_pair(const short* __restrict__ wbuf, const short* __restrict__ xpl,
               const float* __restrict__ scv, const float* __restrict__ offv,
               short* __restrict__ opl)
{
    constexpr int LOUT = LIN / 2;
    constexpr int KST = CIN / 16;
    constexpr int OBS = COUT / 128;
    constexpr int NG = CIN / 8;
    constexpr int SLOTS = LIN / 2 + 1;
    constexpr size_t PLIN = (size_t)32 * NG * 2 * SLOTS * 8;
    constexpr int NF = TILE / 64;               // pos fragments per wave
    constexpr int NGo = COUT / 8;
    constexpr int OSLOTS = (EPI == 0) ? (LOUT / 2 + 1) : (LOUT + 2);
    constexpr size_t PLOUT = (size_t)32 * NGo * ((EPI == 0) ? 2 : 1) * OSLOTS * 8;

    constexpr int XOFF = 49152;      // W: [0,49152) = 2 halves x 1536 slots
    constexpr int SCOFF = 69632;     // sc [SCOFF, +1024), off [+1024, +2048)
    __shared__ __align__(16) char lds[71680];

    const int tid = threadIdx.x;
    const int lane = tid & 63;
    const int wv = tid >> 6;                    // 0..7
    const int wo = wv >> 2;                     // oc-half
    const int wm = (wv >> 1) & 1, wn = wv & 1;
    const int hi = lane >> 5, n32 = lane & 31;
    const int n0 = blockIdx.x * TILE;
    const int oby = blockIdx.y;
    const int o0 = oby * 256;
    const int b = blockIdx.z;

    if (tid < 256) ((float*)(lds + SCOFF))[tid] = scv[o0 + tid];
    else ((float*)(lds + SCOFF + 1024))[tid - 256] = offv[o0 + tid - 256];

    f32x16 acc0[2][2], acc1[2][2];
    #pragma unroll
    for (int i = 0; i < 2; ++i)
        #pragma unroll
        for (int j = 0; j < 2; ++j)
            #pragma unroll
            for (int e = 0; e < 16; ++e) { acc0[i][j][e] = 0.0f; acc1[i][j][e] = 0.0f; }

    #pragma unroll 1
    for (int ks = 0; ks < KST; ++ks) {
        __syncthreads();
        // stage W: each 4-wave group stages its own 128-oc half (24 KB)
        {
            const short* wsrc = wbuf +
                ((size_t)ks * OBS + (oby * 2 + wo)) * 1536 * 8;
            #pragma unroll
            for (int it = 0; it < 6; ++it) {
                int slot0 = it * 256 + (wv & 3) * 64;
                glds16(wsrc + (size_t)(slot0 + lane) * 8,
                       lds + wo * 24576 + slot0 * 16);
            }
        }
        // stage X: 8 runs, one per wave (shared by both oc halves)
        {
            int g0 = ks * 2;
            int r = wv;
            int sg = r >> 2, rhi = (r >> 1) & 1, arr = r & 1;
            int start = arr ? n0 : (n0 + 1);
            int cnt = arr ? (TILE + 1) : TILE;
            const short* src = xpl + (size_t)sg * PLIN
                + ((((size_t)b * NG + (g0 + rhi)) * 2 + arr) * SLOTS + start) * 8;
            char* dst = lds + XOFF + ((sg * 2 + rhi) * 2 + arr) * 2112;
            for (int c0 = 0; c0 < cnt; c0 += 64) {
                if (lane < cnt - c0)
                    glds16(src + (size_t)(c0 + lane) * 8, dst + c0 * 16);
            }
        }
        __syncthreads();
        // compute: 3 taps x {hh, hl, lh} x 2mf x NF nf
        #pragma unroll
        for (int t = 0; t < 3; ++t) {
            half8 af[2][2], bx[2][2];
            #pragma unroll
            for (int s = 0; s < 2; ++s) {
                #pragma unroll
                for (int mf = 0; mf < 2; ++mf)
                    af[s][mf] = *(const half8*)(lds + wo * 24576 +
                        (((t * 2 + s) * 4 + (wm * 2 + mf)) * 64 + lane) * 16);
                int arr = (t == 1) ? 0 : 1;
                int tof = (t == 2) ? 1 : 0;
                #pragma unroll
                for (int nf = 0; nf < NF; ++nf) {
                    int qb = wn * (TILE / 2) + nf * 32 + tof;
                    bx[s][nf] = *(const half8*)(lds + XOFF + s * 8448
                                                + arr * 2112 + qb * 16
                                                + hi * 4224 + n32 * 16);
                }
            }
            #pragma unroll
            for (int mf = 0; mf < 2; ++mf)
                #pragma unroll
                for (int nf = 0; nf < NF; ++nf) {
                    acc0[mf][nf] = __builtin_amdgcn_mfma_f32_32x32x16_f16(
                        af[0][mf], bx[0][nf], acc0[mf][nf], 0, 0, 0);
                    acc1[mf][nf] = __builtin_amdgcn_mfma_f32_32x32x16_f16(
                        af[0][mf], bx[1][nf], acc1[mf][nf], 0, 0, 0);
                    acc1[mf][nf] = __builtin_amdgcn_mfma_f32_32x32x16_f16(
                        af[1][mf], bx[0][nf], acc1[mf][nf], 0, 0, 0);
                }
        }
    }

    // ---- epilogue: combine + affine + lrelu + split to planes
    #pragma unroll
    for (int half = 0; half < NF; ++half) {
        __syncthreads();
        #pragma unroll
        for (int mf = 0; mf < 2; ++mf)
            #pragma unroll
            for (int r = 0; r < 16; ++r) {
                int ocl = mf * 32 + (r & 3) + 8 * (r >> 2) + 4 * hi;
                *(float*)(lds + wv * 8704 + n32 * 272 + ocl * 4) =
                    acc0[mf][half][r] + C14 * acc1[mf][half][r];
            }
        __syncthreads();
        #pragma unroll
        for (int it = 0; it < 4; ++it) {
            int sl = tid + it * 512;             // [0, 2048)
            int w = sl >> 8, rem = sl & 255, p = rem >> 3, grp = rem & 7;
            int wo_ = w >> 2, wm_ = (w >> 1) & 1, wn_ = w & 1;
            f32x4 v0 = *(f32x4*)(lds + w * 8704 + p * 272 + grp * 32);
            f32x4 v1 = *(f32x4*)(lds + w * 8704 + p * 272 + grp * 32 + 16);
            int ocb = wo_ * 128 + wm_ * 64 + grp * 8;   // within 256
            f32x4 s0 = *(f32x4*)(lds + SCOFF + ocb * 4);
            f32x4 s1 = *(f32x4*)(lds + SCOFF + ocb * 4 + 16);
            f32x4 q0 = *(f32x4*)(lds + SCOFF + 1024 + ocb * 4);
            f32x4 q1 = *(f32x4*)(lds + SCOFF + 1024 + ocb * 4 + 16);
            float y[8];
            #pragma unroll
            for (int j = 0; j < 4; ++j) {
                float a = v0[j] * s0[j] + q0[j];
                y[j] = a >= 0.0f ? a : SLOPE * a;
                float c = v1[j] * s1[j] + q1[j];
                y[4 + j] = c >= 0.0f ? c : SLOPE * c;
            }
            int pos_abs = n0 + wn_ * (TILE / 2) + half * 32 + p;
            int oc_abs = o0 + ocb;
            short8 rh, rl;
            #pragma unroll
            for (int j = 0; j < 8; ++j) {
                unsigned short uh, ul;
                split16(y[j], uh, ul);
                rh[j] = (short)uh; rl[j] = (short)ul;
            }
            int gq = oc_abs >> 3;
            size_t base;
            if (EPI == 0) {
                int arr = pos_abs & 1;
                int slot = arr ? (pos_abs + 1) / 2 : pos_abs / 2 + 1;
                base = ((((size_t)b * NGo + gq) * 2 + arr) * OSLOTS + slot) * 8;
            } else {
                base = (((size_t)b * NGo + gq) * OSLOTS + (pos_abs + 1)) * 8;
            }
            *(short8*)(opl + base) = rh;
            *(short8*)(opl + PLOUT + base) = rl;
        }
    }

    // ---- guard slots for the consumer layer (32 ch-groups per block)
    if (EPI == 0) {
        if (blockIdx.x == 0 && tid < 128) {
            int sg = tid >> 6, r2 = tid & 63, g16 = r2 >> 1, a2 = r2 & 1;
            int gq = oby * 32 + g16;
            short8 z;
            #pragma unroll
            for (int j = 0; j < 8; ++j) z[j] = 0;
            *(short8*)(opl + (size_t)sg * PLOUT +
                       ((((size_t)b * NGo + gq) * 2 + a2) * OSLOTS) * 8) = z;
        }
    } else {
        if (tid < 64 && (blockIdx.x == 0 || blockIdx.x == gridDim.x - 1)) {
            int sg = tid >> 5, g16 = tid & 31;
            int gq = oby * 32 + g16;
            int slot = (blockIdx.x == 0) ? 0 : (OSLOTS - 1);
            short8 z;
            #pragma unroll
            for (int j = 0; j < 8; ++j) z[j] = 0;
            *(short8*)(opl + (size_t)sg * PLOUT +
                       (((size_t)b * NGo + gq) * OSLOTS + slot) * 8) = z;
        }
    }
}

// ---------- stride-1 conv (layer 4): 128 oc x 128 pos, 4 waves, fp32 f out ----
template<int CIN, int COUT, int LIN>
__global__ __launch_bounds__(256, 2)
void conv_s1(const short* __restrict__ wbuf, const short* __restrict__ xpl,
             const float* __restrict__ scv, const float* __restrict__ offv,
             float* __restrict__ fout)
{
    constexpr int KST = CIN / 16;
    constexpr int OB = COUT / 128;
    constexpr int NG = CIN / 8;
    constexpr int SLOTS = LIN + 2;
    constexpr size_t PLIN = (size_t)32 * NG * SLOTS * 8;

    constexpr int XOFF = 24576;
    constexpr int BUF  = 41472;
    constexpr int SCOFF = BUF;
    __shared__ __align__(16) char lds[BUF + 1024];

    const int tid = threadIdx.x;
    const int lane = tid & 63;
    const int wv = tid >> 6;
    const int wm = wv >> 1, wn = wv & 1;
    const int hi = lane >> 5, n32 = lane & 31;
    const int n0 = blockIdx.x * 128;
    const int ob = blockIdx.y;
    const int o0 = ob * 128;
    const int b = blockIdx.z;

    if (tid < 128) {
        ((float*)(lds + SCOFF))[tid] = scv[o0 + tid];
        ((float*)(lds + SCOFF + 512))[tid] = offv[o0 + tid];
    }

    f32x16 acc0[2][2], acc1[2][2];
    #pragma unroll
    for (int i = 0; i < 2; ++i)
        #pragma unroll
        for (int j = 0; j < 2; ++j)
            #pragma unroll
            for (int e = 0; e < 16; ++e) { acc0[i][j][e] = 0.0f; acc1[i][j][e] = 0.0f; }

    const short* wg = wbuf + (size_t)ob * 1536 * 8;
    const int lanexoff = hi * 4224 + n32 * 16;

    #pragma unroll 1
    for (int ks = 0; ks < KST; ++ks) {
        __syncthreads();
        {
            const short* wsrc = wg + (size_t)ks * OB * 1536 * 8;
            #pragma unroll
            for (int it = 0; it < 6; ++it) {
                int slot0 = it * 256 + wv * 64;
                glds16(wsrc + (size_t)(slot0 + lane) * 8, lds + slot0 * 16);
            }
        }
        {
            int g0 = ks * 2;
            for (int r = wv; r < 4; r += 4) {
                int sg = r >> 1, rhi = r & 1;
                const short* src = xpl + (size_t)sg * PLIN
                    + (((size_t)b * NG + (g0 + rhi)) * SLOTS + n0) * 8;
                char* dst = lds + XOFF + (sg * 2 + rhi) * 2112;
                for (int c0 = 0; c0 < 130; c0 += 64) {
                    if (lane < 130 - c0)
                        glds16(src + (size_t)(c0 + lane) * 8, dst + c0 * 16);
                }
            }
        }
        __syncthreads();
        #pragma unroll
        for (int t = 0; t < 3; ++t) {
            half8 af[2][2], bx[2][2];
            #pragma unroll
            for (int s = 0; s < 2; ++s) {
                #pragma unroll
                for (int mf = 0; mf < 2; ++mf)
                    af[s][mf] = *(const half8*)(lds +
                        (((t * 2 + s) * 4 + (wm * 2 + mf)) * 64 + lane) * 16);
                #pragma unroll
                for (int nf = 0; nf < 2; ++nf) {
                    int qb = wn * 64 + nf * 32 + t;
                    bx[s][nf] = *(const half8*)(lds + XOFF + s * 4224
                                                + qb * 16 + hi * 2112 + n32 * 16);
                }
            }
            #pragma unroll
            for (int mf = 0; mf < 2; ++mf)
                #pragma unroll
                for (int nf = 0; nf < 2; ++nf) {
                    acc0[mf][nf] = __builtin_amdgcn_mfma_f32_32x32x16_f16(
                        af[0][mf], bx[0][nf], acc0[mf][nf], 0, 0, 0);
                    acc1[mf][nf] = __builtin_amdgcn_mfma_f32_32x32x16_f16(
                        af[0][mf], bx[1][nf], acc1[mf][nf], 0, 0, 0);
                    acc1[mf][nf] = __builtin_amdgcn_mfma_f32_32x32x16_f16(
                        af[1][mf], bx[0][nf], acc1[mf][nf], 0, 0, 0);
                }
        }
    }

    #pragma unroll
    for (int half = 0; half < 2; ++half) {
        __syncthreads();
        #pragma unroll
        for (int mf = 0; mf < 2; ++mf)
            #pragma unroll
            for (int r = 0; r < 16; ++r) {
                int ocl = mf * 32 + (r & 3) + 8 * (r >> 2) + 4 * hi;
                *(float*)(lds + wv * 8704 + n32 * 272 + ocl * 4) =
                    acc0[mf][half][r] + C14 * acc1[mf][half][r];
            }
        __syncthreads();
        #pragma unroll
        for (int it = 0; it < 4; ++it) {
            int sl = tid + it * 256;
            int w = sl >> 8, rem = sl & 255, p = rem >> 3, grp = rem & 7;
            int wm_ = w >> 1, wn_ = w & 1;
            f32x4 v0 = *(f32x4*)(lds + w * 8704 + p * 272 + grp * 32);
            f32x4 v1 = *(f32x4*)(lds + w * 8704 + p * 272 + grp * 32 + 16);
            int oclb = wm_ * 64 + grp * 8;
            f32x4 s0 = *(f32x4*)(lds + SCOFF + oclb * 4);
            f32x4 s1 = *(f32x4*)(lds + SCOFF + oclb * 4 + 16);
            f32x4 q0 = *(f32x4*)(lds + SCOFF + 512 + oclb * 4);
            f32x4 q1 = *(f32x4*)(lds + SCOFF + 512 + oclb * 4 + 16);
            f32x4 w0, w1;
            #pragma unroll
            for (int j = 0; j < 4; ++j) {
                float a = v0[j] * s0[j] + q0[j];
                w0[j] = a >= 0.0f ? a : SLOPE * a;
                float c = v1[j] * s1[j] + q1[j];
                w1[j] = c >= 0.0f ? c : SLOPE * c;
            }
            int pos_abs = n0 + wn_ * 64 + half * 32 + p;
            float* fp = fout + ((size_t)(b * 256 + pos_abs)) * 128 + o0 + oclb;
            *(f32x4*)fp = w0;
            *(f32x4*)(fp + 4) = w1;
        }
    }
}

// ---------- row split: src[N][128] fp32 -> 2 fp16 planes (fragment order) + sumsq
__global__ __launch_bounds__(256)
void split_kernel(const float* __restrict__ src, int nrows,
                  short* __restrict__ ph, short* __restrict__ pl,
                  float* __restrict__ sumv)
{
    int t = blockIdx.x * 256 + threadIdx.x;
    int n = t >> 4, g = t & 15;
    if (n >= nrows) return;
    const float* rowp = src + (size_t)n * 128 + g * 8;
    float4 v0 = *(const float4*)rowp;
    float4 v1 = *(const float4*)(rowp + 4);
    float vv[8] = {v0.x, v0.y, v0.z, v0.w, v1.x, v1.y, v1.z, v1.w};
    short8 rh, rl;
    float ss = 0.0f;
    #pragma unroll
    for (int j = 0; j < 8; ++j) {
        float v = vv[j];
        ss = fmaf(v, v, ss);
        unsigned short uh, ul;
        split16(v, uh, ul);
        rh[j] = (short)uh; rl[j] = (short)ul;
    }
    int nb = n >> 5, m = n & 31, ks = g >> 1, hi = g & 1;
    size_t slot = ((((size_t)nb * 8 + ks) * 2 + hi) * 32 + m) * 8;
    *(short8*)(ph + slot) = rh;
    *(short8*)(pl + slot) = rl;
    #pragma unroll
    for (int mk = 8; mk; mk >>= 1) ss += __shfl_xor(ss, mk);
    if (g == 0) sumv[n] = ss;
}

// ---------- dist tile (128n x 128k): direct-from-global fp16-split MFMA + argmin
__global__ __launch_bounds__(256, 2)
void distmin_kernel(const short* __restrict__ fh, const short* __restrict__ fl,
                    const short* __restrict__ eh, const short* __restrict__ el,
                    const float* __restrict__ sf, const float* __restrict__ se,
                    float* __restrict__ dist, unsigned long long* __restrict__ mp)
{
    __shared__ unsigned long long cand[128 * 64];   // 64 KB
    const int tid = threadIdx.x;
    const int lane = tid & 63;
    const int wv = tid >> 6;
    const int wm = wv >> 1, wn = wv & 1;
    const int hi = lane >> 5, n32 = lane & 31;
    const int kb = blockIdx.x;   // 0..31  (k-tile of 128)
    const int nb = blockIdx.y;   // 0..63  (n-tile of 128)

    f32x16 acc0[2][2], acc1[2][2];
    #pragma unroll
    for (int i = 0; i < 2; ++i)
        #pragma unroll
        for (int j = 0; j < 2; ++j)
            #pragma unroll
            for (int e = 0; e < 16; ++e) { acc0[i][j][e] = 0.0f; acc1[i][j][e] = 0.0f; }

    const short* fb[2][2];
    const short* eb[2][2];
    {
        const short* fpl[2] = {fh, fl};
        const short* epl[2] = {eh, el};
        #pragma unroll
        for (int s = 0; s < 2; ++s) {
            #pragma unroll
            for (int mf = 0; mf < 2; ++mf)
                fb[s][mf] = fpl[s] + (size_t)nb * 16384
                            + ((size_t)(wm * 2 + mf) * 8 * 64 + lane) * 8;
            #pragma unroll
            for (int nf = 0; nf < 2; ++nf)
                eb[s][nf] = epl[s]
                            + ((size_t)(kb * 4 + wn * 2 + nf) * 8 * 64 + lane) * 8;
        }
    }

    #pragma unroll
    for (int ks = 0; ks < 8; ++ks) {
        half8 af[2][2], bx[2][2];
        #pragma unroll
        for (int s = 0; s < 2; ++s) {
            #pragma unroll
            for (int mf = 0; mf < 2; ++mf)
                af[s][mf] = *(const half8*)(fb[s][mf] + ks * 512);
            #pragma unroll
            for (int nf = 0; nf < 2; ++nf)
                bx[s][nf] = *(const half8*)(eb[s][nf] + ks * 512);
        }
        #pragma unroll
        for (int mf = 0; mf < 2; ++mf)
            #pragma unroll
            for (int nf = 0; nf < 2; ++nf) {
                acc0[mf][nf] = __builtin_amdgcn_mfma_f32_32x32x16_f16(
                    af[0][mf], bx[0][nf], acc0[mf][nf], 0, 0, 0);
                acc1[mf][nf] = __builtin_amdgcn_mfma_f32_32x32x16_f16(
                    af[0][mf], bx[1][nf], acc1[mf][nf], 0, 0, 0);
                acc1[mf][nf] = __builtin_amdgcn_mfma_f32_32x32x16_f16(
                    af[1][mf], bx[0][nf], acc1[mf][nf], 0, 0, 0);
            }
    }

    const int n_blk = nb * 128;
    const int kc0 = kb * 128 + wn * 64 + n32;
    const float se0 = se[kc0];
    const float se1 = se[kc0 + 32];
    #pragma unroll
    for (int mf = 0; mf < 2; ++mf) {
        #pragma unroll
        for (int r = 0; r < 16; ++r) {
            int nloc = wm * 64 + mf * 32 + (r & 3) + 8 * (r >> 2) + 4 * hi;
            int n = n_blk + nloc;
            float sfn = sf[n];
            float d0 = acc0[mf][0][r] + C14 * acc1[mf][0][r];
            float d1 = acc0[mf][1][r] + C14 * acc1[mf][1][r];
            float v0 = (sfn + se0) - 2.0f * d0;
            float v1 = (sfn + se1) - 2.0f * d1;
            __builtin_nontemporal_store(v0, &dist[(size_t)n * 4096 + kc0]);
            __builtin_nontemporal_store(v1, &dist[(size_t)n * 4096 + kc0 + 32]);
            unsigned long long p0 =
                (((unsigned long long)__float_as_uint(v0)) << 32) | (unsigned)kc0;
            unsigned long long p1 =
                (((unsigned long long)__float_as_uint(v1)) << 32) | (unsigned)(kc0 + 32);
            unsigned long long p = p1 < p0 ? p1 : p0;
            cand[nloc * 64 + wn * 32 + n32] = p;
        }
    }
    __syncthreads();
    {
        int row = tid >> 1, h = tid & 1;
        unsigned long long best = ~0ULL;
        #pragma unroll
        for (int i = 0; i < 32; ++i) {
            int c = h * 32 + ((i + row) & 31);
            unsigned long long cv = cand[row * 64 + c];
            best = cv < best ? cv : best;
        }
        unsigned lo = (unsigned)best, hw = (unsigned)(best >> 32);
        unsigned lo2 = __shfl_xor(lo, 1), hw2 = __shfl_xor(hw, 1);
        unsigned long long ob = (((unsigned long long)hw2) << 32) | lo2;
        if (ob < best) best = ob;
        if (h == 0) atomicMin(mp + n_blk + row, best);
    }
}

// ---------- unpack codes ----------
__global__ __launch_bounds__(256)
void codes_kernel(const unsigned long long* __restrict__ mp,
                  float* __restrict__ codes)
{
    int n = blockIdx.x * 256 + threadIdx.x;
    if (n < 8192) codes[n] = (float)(unsigned)(mp[n] & 0xffffffffULL);
}

// ---------------------------------------------------------------
extern "C" void kernel_launch(void* const* d_in, const int* in_sizes, int n_in,
                              void* d_out, int out_size, void* d_ws, size_t ws_size,
                              hipStream_t stream)
{
    const float* x   = (const float*)d_in[0];
    const float* w1  = (const float*)d_in[1];
    const float* b1  = (const float*)d_in[2];
    const float* w2  = (const float*)d_in[3];
    const float* b2  = (const float*)d_in[4];
    const float* w3  = (const float*)d_in[5];
    const float* b3  = (const float*)d_in[6];
    const float* w4  = (const float*)d_in[7];
    const float* b4  = (const float*)d_in[8];
    const float* g1  = (const float*)d_in[9];
    const float* be1 = (const float*)d_in[10];
    const float* m1  = (const float*)d_in[11];
    const float* v1  = (const float*)d_in[12];
    const float* g2  = (const float*)d_in[13];
    const float* be2 = (const float*)d_in[14];
    const float* m2  = (const float*)d_in[15];
    const float* v2  = (const float*)d_in[16];
    const float* g3  = (const float*)d_in[17];
    const float* be3 = (const float*)d_in[18];
    const float* m3  = (const float*)d_in[19];
    const float* v3  = (const float*)d_in[20];
    const float* g4  = (const float*)d_in[21];
    const float* be4 = (const float*)d_in[22];
    const float* m4  = (const float*)d_in[23];
    const float* v4  = (const float*)d_in[24];
    const float* emb = (const float*)d_in[25];

    float* outf  = (float*)d_out;
    float* codes = outf;
    float* distm = outf + 8192;

    // ---- workspace layout (bytes)
    char* wsb = (char*)d_ws;
    short* wb1 = (short*)(wsb + 0);              // 16*2*1536*16 =   786,432
    short* wb2 = (short*)(wsb + 786432);         // 16*4*1536*16 = 1,572,864
    short* wb3 = (short*)(wsb + 2359296);        // 32*4*1536*16 = 3,145,728
    short* wb4 = (short*)(wsb + 5505024);        // 32*1*1536*16 =   786,432
    float* sc1 = (float*)(wsb + 6291456); float* off1 = sc1 + 256;
    float* sc2 = (float*)(wsb + 6293504); float* off2 = sc2 + 512;
    float* sc3 = (float*)(wsb + 6297600); float* off3 = sc3 + 512;
    float* sc4 = (float*)(wsb + 6301696); float* off4 = sc4 + 128;
    short* h1p = (short*)(wsb + 6302720);        // 2*16,809,984 = 33,619,968
    short* fh  = (short*)(wsb + 39922688);       // 2,097,152 each
    short* fl  = (short*)(wsb + 42019840);
    short* eh  = (short*)(wsb + 44116992);       // 1,048,576 each
    short* el  = (short*)(wsb + 45165568);
    float* sf  = (float*)(wsb + 46214144);       // 32,768
    float* se  = (float*)(wsb + 46246912);       // 16,384
    unsigned long long* mp = (unsigned long long*)(wsb + 46263296);  // 65,536

    // ---- large scratch in the (dead-until-dist) dist region of d_out
    char* db = (char*)distm;
    short* xpl = (short*)db;                      // L1 input planes
    short* h2p = (short*)db;                      // L2 output planes
    short* h3p = (short*)(db + 33685504);         // L3 output planes
    float* f   = (float*)(db + 80000000);         // fp32 features [8192][128]

    // ---- prep
    wprep_all<<<dim3(192, 4), 256, 0, stream>>>(w1, wb1, w2, wb2, w3, wb3, w4, wb4);
    bnprep_init<<<38, 256, 0, stream>>>(
        g1, be1, m1, v1, b1, sc1, off1,
        g2, be2, m2, v2, b2, sc2, off2,
        g3, be3, m3, v3, b3, sc3, off3,
        g4, be4, m4, v4, b4, sc4, off4, mp);
    split_kernel<<<256, 256, 0, stream>>>(emb, 4096, eh, el, se);

    // ---- input split + conv stack
    xsplit<<<dim3(8, 32, 32), 256, 0, stream>>>(x, xpl);
    conv_pair<256, 256, 2048, 128, 0>
        <<<dim3(8, 1, 32), 512, 0, stream>>>(wb1, xpl, sc1, off1, h1p);
    conv_pair<256, 512, 1024, 128, 0>
        <<<dim3(4, 2, 32), 512, 0, stream>>>(wb2, h1p, sc2, off2, h2p);
    conv_pair<512, 512, 512, 64, 1>
        <<<dim3(4, 2, 32), 512, 0, stream>>>(wb3, h2p, sc3, off3, h3p);
    conv_s1<512, 128, 256>
        <<<dim3(2, 1, 32), 256, 0, stream>>>(wb4, h3p, sc4, off4, f);

    // ---- VQ: split f, MFMA distance + fused argmin, unpack codes
    split_kernel<<<512, 256, 0, stream>>>(f, 8192, fh, fl, sf);
    distmin_kernel<<<dim3(32, 64), 256, 0, stream>>>(fh, fl, eh, el,
                                                     sf, se, distm, mp);
    codes_kernel<<<32, 256, 0, stream>>>(mp, codes);
}

// Round 10
// 261.403 us; speedup vs baseline: 1.0093x; 1.0093x over previous
//
#include <hip/hip_runtime.h>
#include <cstdint>
#include <math.h>

#define EPS_BN 1e-5f
#define SLOPE 0.01f
#define C14 6.103515625e-5f     // 2^-14 combine factor
#define SC14 16384.0f           // 2^14 residual scale
#define HMIN 6.103515625e-5f    // fp16 min normal

typedef __attribute__((ext_vector_type(8))) _Float16 half8;
typedef __attribute__((ext_vector_type(8))) short short8;
typedef __attribute__((ext_vector_type(16))) float f32x16;
typedef __attribute__((ext_vector_type(4))) float f32x4;

// 2-way fp16 split: v = h + 2^-14 * l
__device__ __forceinline__ void split16(float v, unsigned short& uh,
                                        unsigned short& ul) {
    _Float16 h = (_Float16)v;
    if (fabsf(v) < HMIN) h = (_Float16)0.0f;
    float rem = v - (float)h;
    _Float16 l = (_Float16)(rem * SC14);
    uh = __builtin_bit_cast(unsigned short, h);
    ul = __builtin_bit_cast(unsigned short, l);
}

typedef const __attribute__((address_space(1))) unsigned int* gas_ptr;
typedef __attribute__((address_space(3))) unsigned int* las_ptr;
__device__ __forceinline__ void glds16(const void* g, void* l) {
    __builtin_amdgcn_global_load_lds((gas_ptr)g, (las_ptr)l, 16, 0, 0);
}

// counted-vmcnt wait (T4): drains all but the newest N VMEM ops
template<int N>
__device__ __forceinline__ void vm_wait() {
    if constexpr (N == 0)      asm volatile("s_waitcnt vmcnt(0)" ::: "memory");
    else if constexpr (N == 8) asm volatile("s_waitcnt vmcnt(8)" ::: "memory");
    else if constexpr (N == 9) asm volatile("s_waitcnt vmcnt(9)" ::: "memory");
}
__device__ __forceinline__ void raw_bar() {
    asm volatile("" ::: "memory");
    __builtin_amdgcn_s_barrier();
    asm volatile("" ::: "memory");
}

// ---------- weight prep, ALL layers ----------
__global__ __launch_bounds__(256)
void wprep_all(const float* __restrict__ w1, short* __restrict__ o1,
               const float* __restrict__ w2, short* __restrict__ o2,
               const float* __restrict__ w3, short* __restrict__ o3,
               const float* __restrict__ w4, short* __restrict__ o4)
{
    const float* w; short* wbuf; int CIN, COUT;
    switch (blockIdx.y) {
        case 0: w = w1; wbuf = o1; CIN = 256; COUT = 256; break;
        case 1: w = w2; wbuf = o2; CIN = 256; COUT = 512; break;
        case 2: w = w3; wbuf = o3; CIN = 512; COUT = 512; break;
        default: w = w4; wbuf = o4; CIN = 512; COUT = 128; break;
    }
    int KST = CIN / 16, OB = COUT / 128;
    int total = KST * OB * 1536;
    for (int sid = blockIdx.x * 256 + threadIdx.x; sid < total;
         sid += gridDim.x * 256) {
        int slot = sid % 1536;
        int kb = sid / 1536;
        int ob = kb % OB, ks = kb / OB;
        int m = slot & 31, hi = (slot >> 5) & 1, mf = (slot >> 6) & 3;
        int ts = slot >> 8;
        int t = ts >> 1, s = ts & 1;
        int oc = ob * 128 + mf * 32 + m;
        int ib = ks * 16 + hi * 8;
        short8 r;
        #pragma unroll
        for (int j = 0; j < 8; ++j) {
            float v = w[((size_t)oc * CIN + ib + j) * 3 + t];
            unsigned short uh, ul;
            split16(v, uh, ul);
            r[j] = (short)(s == 0 ? uh : ul);
        }
        *(short8*)(wbuf + (size_t)sid * 8) = r;
    }
}

// ---------- BN affine prep + mp init + sf zero ----------
__global__ __launch_bounds__(256)
void bnprep_init(
    const float* __restrict__ g1, const float* __restrict__ be1,
    const float* __restrict__ m1, const float* __restrict__ v1,
    const float* __restrict__ b1, float* __restrict__ sc1, float* __restrict__ off1,
    const float* __restrict__ g2, const float* __restrict__ be2,
    const float* __restrict__ m2, const float* __restrict__ v2,
    const float* __restrict__ b2, float* __restrict__ sc2, float* __restrict__ off2,
    const float* __restrict__ g3, const float* __restrict__ be3,
    const float* __restrict__ m3, const float* __restrict__ v3,
    const float* __restrict__ b3, float* __restrict__ sc3, float* __restrict__ off3,
    const float* __restrict__ g4, const float* __restrict__ be4,
    const float* __restrict__ m4, const float* __restrict__ v4,
    const float* __restrict__ b4, float* __restrict__ sc4, float* __restrict__ off4,
    unsigned long long* __restrict__ mp, float* __restrict__ sf)
{
    int bid = blockIdx.x;
    if (bid >= 38) { sf[(bid - 38) * 256 + threadIdx.x] = 0.0f; return; }
    if (bid >= 6) { mp[(bid - 6) * 256 + threadIdx.x] = ~0ULL; return; }
    const float *g, *be, *m, *v, *bias;
    float *sc, *off;
    int c;
    if (bid == 0) {
        g = g1; be = be1; m = m1; v = v1; bias = b1; sc = sc1; off = off1;
        c = threadIdx.x;
    } else if (bid <= 2) {
        g = g2; be = be2; m = m2; v = v2; bias = b2; sc = sc2; off = off2;
        c = (bid - 1) * 256 + threadIdx.x;
    } else if (bid <= 4) {
        g = g3; be = be3; m = m3; v = v3; bias = b3; sc = sc3; off = off3;
        c = (bid - 3) * 256 + threadIdx.x;
    } else {
        g = g4; be = be4; m = m4; v = v4; bias = b4; sc = sc4; off = off4;
        c = threadIdx.x;
        if (c >= 128) return;
    }
    float s = g[c] / sqrtf(v[c] + EPS_BN);
    sc[c] = s;
    off[c] = (bias[c] - m[c]) * s + be[c];
}

// ---------- x split ----------
__global__ __launch_bounds__(256)
void xsplit(const float* __restrict__ x, short* __restrict__ xpl)
{
    const size_t PL = (size_t)32 * 32 * 2 * 1025 * 8;
    int l = blockIdx.x * 256 + threadIdx.x;
    int g = blockIdx.y, b = blockIdx.z;
    float v[8];
    #pragma unroll
    for (int j = 0; j < 8; ++j)
        v[j] = x[((size_t)b * 256 + g * 8 + j) * 2048 + l];
    int arr = l & 1;
    int slot = arr ? (l + 1) / 2 : l / 2 + 1;
    size_t base = ((((size_t)b * 32 + g) * 2 + arr) * 1025 + slot) * 8;
    short8 rh, rl;
    #pragma unroll
    for (int j = 0; j < 8; ++j) {
        unsigned short uh, ul;
        split16(v[j], uh, ul);
        rh[j] = (short)uh; rl[j] = (short)ul;
    }
    *(short8*)(xpl + base) = rh;
    *(short8*)(xpl + PL + base) = rl;
    if (l == 0) {
        short8 z;
        #pragma unroll
        for (int j = 0; j < 8; ++j) z[j] = 0;
        for (int sg = 0; sg < 2; ++sg)
            for (int a2 = 0; a2 < 2; ++a2)
                *(short8*)(xpl + sg * PL +
                           ((((size_t)b * 32 + g) * 2 + a2) * 1025) * 8) = z;
    }
}

// ---------- paired-OC conv (stride 2) with counted-vmcnt pipeline ----------
// dbuf LDS; per step: STAGE(next) -> vmcnt(SCNT) -> bar -> MFMA -> bar.
template<int CIN, int COUT, int LIN, int TILE, int EPI>
__global__ __launch_bounds__(512, 1)
void conv_pair(const short* __restrict__ wbuf, const short* __restrict__ xpl,
               const float* __restrict__ scv, const float* __restrict__ offv,
               short* __restrict__ opl)
{
    constexpr int LOUT = LIN / 2;
    constexpr int KST = CIN / 16;
    constexpr int OBS = COUT / 128;
    constexpr int NG = CIN / 8;
    constexpr int SLOTS = LIN / 2 + 1;
    constexpr size_t PLIN = (size_t)32 * NG * 2 * SLOTS * 8;
    constexpr int NF = TILE / 64;
    constexpr int NGo = COUT / 8;
    constexpr int OSLOTS = (EPI == 0) ? (LOUT / 2 + 1) : (LOUT + 2);
    constexpr size_t PLOUT = (size_t)32 * NGo * ((EPI == 0) ? 2 : 1) * OSLOTS * 8;

    constexpr int XOFF = 49152;              // W: [0,49152) per buffer
    constexpr int BUF  = XOFF + 8 * 2112;    // 66048 per buffer
    constexpr int SCOFF = 2 * BUF;           // 132096
    constexpr int SCNT = (TILE == 128) ? 9 : 8;   // glds16 per wave per stage
    __shared__ __align__(16) char lds[2 * BUF + 2048];

    const int tid = threadIdx.x;
    const int lane = tid & 63;
    const int wv = tid >> 6;
    const int wo = wv >> 2;
    const int wm = (wv >> 1) & 1, wn = wv & 1;
    const int hi = lane >> 5, n32 = lane & 31;
    const int n0 = blockIdx.x * TILE;
    const int oby = blockIdx.y;
    const int o0 = oby * 256;
    const int b = blockIdx.z;

    if (tid < 256) ((float*)(lds + SCOFF))[tid] = scv[o0 + tid];
    else ((float*)(lds + SCOFF + 1024))[tid - 256] = offv[o0 + tid - 256];

    f32x16 acc0[2][2], acc1[2][2];
    #pragma unroll
    for (int i = 0; i < 2; ++i)
        #pragma unroll
        for (int j = 0; j < 2; ++j)
            #pragma unroll
            for (int e = 0; e < 16; ++e) { acc0[i][j][e] = 0.0f; acc1[i][j][e] = 0.0f; }

    // stage: uniform SCNT glds16 per wave (dup loads pad to fixed count)
    auto stage = [&](char* base, int ks) {
        const short* wsrc = wbuf + ((size_t)ks * OBS + (oby * 2 + wo)) * 1536 * 8;
        #pragma unroll
        for (int it = 0; it < 6; ++it) {
            int slot0 = it * 256 + (wv & 3) * 64;
            glds16(wsrc + (size_t)(slot0 + lane) * 8, base + wo * 24576 + slot0 * 16);
        }
        int g0 = ks * 2;
        int sg = wv >> 2, rhi = (wv >> 1) & 1, arr = wv & 1;
        int start = arr ? n0 : (n0 + 1);
        const short* src = xpl + (size_t)sg * PLIN
            + ((((size_t)b * NG + (g0 + rhi)) * 2 + arr) * SLOTS + start) * 8;
        char* dst = base + XOFF + ((sg * 2 + rhi) * 2 + arr) * 2112;
        if (TILE == 128) {
            glds16(src + (size_t)lane * 8, dst);
            glds16(src + (size_t)(64 + lane) * 8, dst + 64 * 16);
            int c2 = arr ? 65 : 64;                 // arr=0: idempotent dup
            glds16(src + (size_t)(c2 + lane) * 8, dst + c2 * 16);
        } else {
            glds16(src + (size_t)lane * 8, dst);
            int c1 = arr ? 1 : 0;                   // arr=0: idempotent dup
            glds16(src + (size_t)(c1 + lane) * 8, dst + c1 * 16);
        }
    };

    stage(lds, 0);

    #pragma unroll 1
    for (int ks = 0; ks < KST; ++ks) {
        char* cbase = lds + (ks & 1) * BUF;
        char* nbase = lds + ((ks & 1) ^ 1) * BUF;
        if (ks + 1 < KST) {
            stage(nbase, ks + 1);
            vm_wait<SCNT>();        // drain prev buffer's loads only
        } else {
            vm_wait<0>();
        }
        raw_bar();                   // buf[cur] ready chip-wide
        __builtin_amdgcn_s_setprio(1);
        #pragma unroll
        for (int t = 0; t < 3; ++t) {
            half8 af[2][2], bx[2][2];
            #pragma unroll
            for (int s = 0; s < 2; ++s) {
                #pragma unroll
                for (int mf = 0; mf < 2; ++mf)
                    af[s][mf] = *(const half8*)(cbase + wo * 24576 +
                        (((t * 2 + s) * 4 + (wm * 2 + mf)) * 64 + lane) * 16);
                int arr = (t == 1) ? 0 : 1;
                int tof = (t == 2) ? 1 : 0;
                #pragma unroll
                for (int nf = 0; nf < NF; ++nf) {
                    int qb = wn * (TILE / 2) + nf * 32 + tof;
                    bx[s][nf] = *(const half8*)(cbase + XOFF + s * 8448
                                                + arr * 2112 + qb * 16
                                                + hi * 4224 + n32 * 16);
                }
            }
            #pragma unroll
            for (int mf = 0; mf < 2; ++mf)
                #pragma unroll
                for (int nf = 0; nf < NF; ++nf) {
                    acc0[mf][nf] = __builtin_amdgcn_mfma_f32_32x32x16_f16(
                        af[0][mf], bx[0][nf], acc0[mf][nf], 0, 0, 0);
                    acc1[mf][nf] = __builtin_amdgcn_mfma_f32_32x32x16_f16(
                        af[0][mf], bx[1][nf], acc1[mf][nf], 0, 0, 0);
                    acc1[mf][nf] = __builtin_amdgcn_mfma_f32_32x32x16_f16(
                        af[1][mf], bx[0][nf], acc1[mf][nf], 0, 0, 0);
                }
        }
        __builtin_amdgcn_s_setprio(0);
        raw_bar();                   // all reads of buf[cur] done -> reusable
    }

    // ---- epilogue ----
    #pragma unroll
    for (int half = 0; half < NF; ++half) {
        __syncthreads();
        #pragma unroll
        for (int mf = 0; mf < 2; ++mf)
            #pragma unroll
            for (int r = 0; r < 16; ++r) {
                int ocl = mf * 32 + (r & 3) + 8 * (r >> 2) + 4 * hi;
                *(float*)(lds + wv * 8704 + n32 * 272 + ocl * 4) =
                    acc0[mf][half][r] + C14 * acc1[mf][half][r];
            }
        __syncthreads();
        #pragma unroll
        for (int it = 0; it < 4; ++it) {
            int sl = tid + it * 512;
            int w = sl >> 8, rem = sl & 255, p = rem >> 3, grp = rem & 7;
            int wo_ = w >> 2, wm_ = (w >> 1) & 1, wn_ = w & 1;
            f32x4 v0 = *(f32x4*)(lds + w * 8704 + p * 272 + grp * 32);
            f32x4 v1 = *(f32x4*)(lds + w * 8704 + p * 272 + grp * 32 + 16);
            int ocb = wo_ * 128 + wm_ * 64 + grp * 8;
            f32x4 s0 = *(f32x4*)(lds + SCOFF + ocb * 4);
            f32x4 s1 = *(f32x4*)(lds + SCOFF + ocb * 4 + 16);
            f32x4 q0 = *(f32x4*)(lds + SCOFF + 1024 + ocb * 4);
            f32x4 q1 = *(f32x4*)(lds + SCOFF + 1024 + ocb * 4 + 16);
            float y[8];
            #pragma unroll
            for (int j = 0; j < 4; ++j) {
                float a = v0[j] * s0[j] + q0[j];
                y[j] = a >= 0.0f ? a : SLOPE * a;
                float c = v1[j] * s1[j] + q1[j];
                y[4 + j] = c >= 0.0f ? c : SLOPE * c;
            }
            int pos_abs = n0 + wn_ * (TILE / 2) + half * 32 + p;
            int oc_abs = o0 + ocb;
            short8 rh, rl;
            #pragma unroll
            for (int j = 0; j < 8; ++j) {
                unsigned short uh, ul;
                split16(y[j], uh, ul);
                rh[j] = (short)uh; rl[j] = (short)ul;
            }
            int gq = oc_abs >> 3;
            size_t base;
            if (EPI == 0) {
                int arr = pos_abs & 1;
                int slot = arr ? (pos_abs + 1) / 2 : pos_abs / 2 + 1;
                base = ((((size_t)b * NGo + gq) * 2 + arr) * OSLOTS + slot) * 8;
            } else {
                base = (((size_t)b * NGo + gq) * OSLOTS + (pos_abs + 1)) * 8;
            }
            *(short8*)(opl + base) = rh;
            *(short8*)(opl + PLOUT + base) = rl;
        }
    }

    if (EPI == 0) {
        if (blockIdx.x == 0 && tid < 128) {
            int sg = tid >> 6, r2 = tid & 63, g16 = r2 >> 1, a2 = r2 & 1;
            int gq = oby * 32 + g16;
            short8 z;
            #pragma unroll
            for (int j = 0; j < 8; ++j) z[j] = 0;
            *(short8*)(opl + (size_t)sg * PLOUT +
                       ((((size_t)b * NGo + gq) * 2 + a2) * OSLOTS) * 8) = z;
        }
    } else {
        if (tid < 64 && (blockIdx.x == 0 || blockIdx.x == gridDim.x - 1)) {
            int sg = tid >> 5, g16 = tid & 31;
            int gq = oby * 32 + g16;
            int slot = (blockIdx.x == 0) ? 0 : (OSLOTS - 1);
            short8 z;
            #pragma unroll
            for (int j = 0; j < 8; ++j) z[j] = 0;
            *(short8*)(opl + (size_t)sg * PLOUT +
                       (((size_t)b * NGo + gq) * OSLOTS + slot) * 8) = z;
        }
    }
}

// ---------- stride-1 conv (layer 4), pipelined; fused feature-split + sumsq ----
template<int CIN, int COUT, int LIN>
__global__ __launch_bounds__(256, 2)
void conv_s1(const short* __restrict__ wbuf, const short* __restrict__ xpl,
             const float* __restrict__ scv, const float* __restrict__ offv,
             short* __restrict__ fh, short* __restrict__ fl,
             float* __restrict__ sf)
{
    constexpr int KST = CIN / 16;
    constexpr int NG = CIN / 8;
    constexpr int SLOTS = LIN + 2;
    constexpr size_t PLIN = (size_t)32 * NG * SLOTS * 8;

    constexpr int XOFF = 24576;
    constexpr int BUF  = XOFF + 4 * 2112;    // 33024
    constexpr int SCOFF = 2 * BUF;           // 66048
    __shared__ __align__(16) char lds[2 * BUF + 1024];

    const int tid = threadIdx.x;
    const int lane = tid & 63;
    const int wv = tid >> 6;
    const int wm = wv >> 1, wn = wv & 1;
    const int hi = lane >> 5, n32 = lane & 31;
    const int n0 = blockIdx.x * 128;
    const int b = blockIdx.z;

    if (tid < 128) {
        ((float*)(lds + SCOFF))[tid] = scv[tid];
        ((float*)(lds + SCOFF + 512))[tid] = offv[tid];
    }

    f32x16 acc0[2][2], acc1[2][2];
    #pragma unroll
    for (int i = 0; i < 2; ++i)
        #pragma unroll
        for (int j = 0; j < 2; ++j)
            #pragma unroll
            for (int e = 0; e < 16; ++e) { acc0[i][j][e] = 0.0f; acc1[i][j][e] = 0.0f; }

    auto stage = [&](char* base, int ks) {
        const short* wsrc = wbuf + (size_t)ks * 1536 * 8;
        #pragma unroll
        for (int it = 0; it < 6; ++it) {
            int slot0 = it * 256 + wv * 64;
            glds16(wsrc + (size_t)(slot0 + lane) * 8, base + slot0 * 16);
        }
        int g0 = ks * 2;
        int sg = wv >> 1, rhi = wv & 1;
        const short* src = xpl + (size_t)sg * PLIN
            + (((size_t)b * NG + (g0 + rhi)) * SLOTS + n0) * 8;
        char* dst = base + XOFF + (sg * 2 + rhi) * 2112;
        glds16(src + (size_t)lane * 8, dst);
        glds16(src + (size_t)(64 + lane) * 8, dst + 64 * 16);
        glds16(src + (size_t)(66 + lane) * 8, dst + 66 * 16);  // covers 66..129
    };

    stage(lds, 0);

    #pragma unroll 1
    for (int ks = 0; ks < KST; ++ks) {
        char* cbase = lds + (ks & 1) * BUF;
        char* nbase = lds + ((ks & 1) ^ 1) * BUF;
        if (ks + 1 < KST) {
            stage(nbase, ks + 1);
            vm_wait<9>();
        } else {
            vm_wait<0>();
        }
        raw_bar();
        __builtin_amdgcn_s_setprio(1);
        #pragma unroll
        for (int t = 0; t < 3; ++t) {
            half8 af[2][2], bx[2][2];
            #pragma unroll
            for (int s = 0; s < 2; ++s) {
                #pragma unroll
                for (int mf = 0; mf < 2; ++mf)
                    af[s][mf] = *(const half8*)(cbase +
                        (((t * 2 + s) * 4 + (wm * 2 + mf)) * 64 + lane) * 16);
                #pragma unroll
                for (int nf = 0; nf < 2; ++nf) {
                    int qb = wn * 64 + nf * 32 + t;
                    bx[s][nf] = *(const half8*)(cbase + XOFF + s * 4224
                                                + qb * 16 + hi * 2112 + n32 * 16);
                }
            }
            #pragma unroll
            for (int mf = 0; mf < 2; ++mf)
                #pragma unroll
                for (int nf = 0; nf < 2; ++nf) {
                    acc0[mf][nf] = __builtin_amdgcn_mfma_f32_32x32x16_f16(
                        af[0][mf], bx[0][nf], acc0[mf][nf], 0, 0, 0);
                    acc1[mf][nf] = __builtin_amdgcn_mfma_f32_32x32x16_f16(
                        af[0][mf], bx[1][nf], acc1[mf][nf], 0, 0, 0);
                    acc1[mf][nf] = __builtin_amdgcn_mfma_f32_32x32x16_f16(
                        af[1][mf], bx[0][nf], acc1[mf][nf], 0, 0, 0);
                }
        }
        __builtin_amdgcn_s_setprio(0);
        raw_bar();
    }

    // ---- epilogue: combine + affine + lrelu + DIRECT split-planes + sumsq ----
    #pragma unroll
    for (int half = 0; half < 2; ++half) {
        __syncthreads();
        #pragma unroll
        for (int mf = 0; mf < 2; ++mf)
            #pragma unroll
            for (int r = 0; r < 16; ++r) {
                int ocl = mf * 32 + (r & 3) + 8 * (r >> 2) + 4 * hi;
                *(float*)(lds + wv * 8704 + n32 * 272 + ocl * 4) =
                    acc0[mf][half][r] + C14 * acc1[mf][half][r];
            }
        __syncthreads();
        #pragma unroll
        for (int it = 0; it < 4; ++it) {
            int sl = tid + it * 256;
            int w = sl >> 8, rem = sl & 255, p = rem >> 3, grp = rem & 7;
            int wm_ = w >> 1, wn_ = w & 1;
            f32x4 v0 = *(f32x4*)(lds + w * 8704 + p * 272 + grp * 32);
            f32x4 v1 = *(f32x4*)(lds + w * 8704 + p * 272 + grp * 32 + 16);
            int oclb = wm_ * 64 + grp * 8;
            f32x4 s0 = *(f32x4*)(lds + SCOFF + oclb * 4);
            f32x4 s1 = *(f32x4*)(lds + SCOFF + oclb * 4 + 16);
            f32x4 q0 = *(f32x4*)(lds + SCOFF + 512 + oclb * 4);
            f32x4 q1 = *(f32x4*)(lds + SCOFF + 512 + oclb * 4 + 16);
            float y[8];
            #pragma unroll
            for (int j = 0; j < 4; ++j) {
                float a = v0[j] * s0[j] + q0[j];
                y[j] = a >= 0.0f ? a : SLOPE * a;
                float c = v1[j] * s1[j] + q1[j];
                y[4 + j] = c >= 0.0f ? c : SLOPE * c;
            }
            int pos_abs = n0 + wn_ * 64 + half * 32 + p;
            int n = b * 256 + pos_abs;
            short8 rh, rl;
            float partial = 0.0f;
            #pragma unroll
            for (int j = 0; j < 8; ++j) {
                partial = fmaf(y[j], y[j], partial);
                unsigned short uh, ul;
                split16(y[j], uh, ul);
                rh[j] = (short)uh; rl[j] = (short)ul;
            }
            int g = wm_ * 8 + grp;              // channel-group 0..15
            size_t slot = ((((size_t)(n >> 5) * 8 + (g >> 1)) * 2 + (g & 1)) * 32
                           + (n & 31)) * 8;
            *(short8*)(fh + slot) = rh;
            *(short8*)(fl + slot) = rl;
            atomicAdd(sf + n, partial);         // sf shifts rows uniformly: argmin-safe
        }
    }
}

// ---------- row split (emb only): fp32 -> 2 fp16 planes + sumsq ----------
__global__ __launch_bounds__(256)
void split_kernel(const float* __restrict__ src, int nrows,
                  short* __restrict__ ph, short* __restrict__ pl,
                  float* __restrict__ sumv)
{
    int t = blockIdx.x * 256 + threadIdx.x;
    int n = t >> 4, g = t & 15;
    if (n >= nrows) return;
    const float* rowp = src + (size_t)n * 128 + g * 8;
    float4 v0 = *(const float4*)rowp;
    float4 v1 = *(const float4*)(rowp + 4);
    float vv[8] = {v0.x, v0.y, v0.z, v0.w, v1.x, v1.y, v1.z, v1.w};
    short8 rh, rl;
    float ss = 0.0f;
    #pragma unroll
    for (int j = 0; j < 8; ++j) {
        float v = vv[j];
        ss = fmaf(v, v, ss);
        unsigned short uh, ul;
        split16(v, uh, ul);
        rh[j] = (short)uh; rl[j] = (short)ul;
    }
    int nb = n >> 5, m = n & 31, ks = g >> 1, hi = g & 1;
    size_t slot = ((((size_t)nb * 8 + ks) * 2 + hi) * 32 + m) * 8;
    *(short8*)(ph + slot) = rh;
    *(short8*)(pl + slot) = rl;
    #pragma unroll
    for (int mk = 8; mk; mk >>= 1) ss += __shfl_xor(ss, mk);
    if (g == 0) sumv[n] = ss;
}

// ---------- dist tile (128n x 128k): direct-from-global fp16-split MFMA + argmin
__global__ __launch_bounds__(256, 2)
void distmin_kernel(const short* __restrict__ fh, const short* __restrict__ fl,
                    const short* __restrict__ eh, const short* __restrict__ el,
                    const float* __restrict__ sf, const float* __restrict__ se,
                    float* __restrict__ dist, unsigned long long* __restrict__ mp)
{
    __shared__ unsigned long long cand[128 * 64];   // 64 KB
    const int tid = threadIdx.x;
    const int lane = tid & 63;
    const int wv = tid >> 6;
    const int wm = wv >> 1, wn = wv & 1;
    const int hi = lane >> 5, n32 = lane & 31;
    const int kb = blockIdx.x;
    const int nb = blockIdx.y;

    f32x16 acc0[2][2], acc1[2][2];
    #pragma unroll
    for (int i = 0; i < 2; ++i)
        #pragma unroll
        for (int j = 0; j < 2; ++j)
            #pragma unroll
            for (int e = 0; e < 16; ++e) { acc0[i][j][e] = 0.0f; acc1[i][j][e] = 0.0f; }

    const short* fb[2][2];
    const short* eb[2][2];
    {
        const short* fpl[2] = {fh, fl};
        const short* epl[2] = {eh, el};
        #pragma unroll
        for (int s = 0; s < 2; ++s) {
            #pragma unroll
            for (int mf = 0; mf < 2; ++mf)
                fb[s][mf] = fpl[s] + (size_t)nb * 16384
                            + ((size_t)(wm * 2 + mf) * 8 * 64 + lane) * 8;
            #pragma unroll
            for (int nf = 0; nf < 2; ++nf)
                eb[s][nf] = epl[s]
                            + ((size_t)(kb * 4 + wn * 2 + nf) * 8 * 64 + lane) * 8;
        }
    }

    #pragma unroll
    for (int ks = 0; ks < 8; ++ks) {
        half8 af[2][2], bx[2][2];
        #pragma unroll
        for (int s = 0; s < 2; ++s) {
            #pragma unroll
            for (int mf = 0; mf < 2; ++mf)
                af[s][mf] = *(const half8*)(fb[s][mf] + ks * 512);
            #pragma unroll
            for (int nf = 0; nf < 2; ++nf)
                bx[s][nf] = *(const half8*)(eb[s][nf] + ks * 512);
        }
        #pragma unroll
        for (int mf = 0; mf < 2; ++mf)
            #pragma unroll
            for (int nf = 0; nf < 2; ++nf) {
                acc0[mf][nf] = __builtin_amdgcn_mfma_f32_32x32x16_f16(
                    af[0][mf], bx[0][nf], acc0[mf][nf], 0, 0, 0);
                acc1[mf][nf] = __builtin_amdgcn_mfma_f32_32x32x16_f16(
                    af[0][mf], bx[1][nf], acc1[mf][nf], 0, 0, 0);
                acc1[mf][nf] = __builtin_amdgcn_mfma_f32_32x32x16_f16(
                    af[1][mf], bx[0][nf], acc1[mf][nf], 0, 0, 0);
            }
    }

    const int n_blk = nb * 128;
    const int kc0 = kb * 128 + wn * 64 + n32;
    const float se0 = se[kc0];
    const float se1 = se[kc0 + 32];
    #pragma unroll
    for (int mf = 0; mf < 2; ++mf) {
        #pragma unroll
        for (int r = 0; r < 16; ++r) {
            int nloc = wm * 64 + mf * 32 + (r & 3) + 8 * (r >> 2) + 4 * hi;
            int n = n_blk + nloc;
            float sfn = sf[n];
            float d0 = acc0[mf][0][r] + C14 * acc1[mf][0][r];
            float d1 = acc0[mf][1][r] + C14 * acc1[mf][1][r];
            float v0 = (sfn + se0) - 2.0f * d0;
            float v1 = (sfn + se1) - 2.0f * d1;
            __builtin_nontemporal_store(v0, &dist[(size_t)n * 4096 + kc0]);
            __builtin_nontemporal_store(v1, &dist[(size_t)n * 4096 + kc0 + 32]);
            unsigned long long p0 =
                (((unsigned long long)__float_as_uint(v0)) << 32) | (unsigned)kc0;
            unsigned long long p1 =
                (((unsigned long long)__float_as_uint(v1)) << 32) | (unsigned)(kc0 + 32);
            unsigned long long p = p1 < p0 ? p1 : p0;
            cand[nloc * 64 + wn * 32 + n32] = p;
        }
    }
    __syncthreads();
    {
        int row = tid >> 1, h = tid & 1;
        unsigned long long best = ~0ULL;
        #pragma unroll
        for (int i = 0; i < 32; ++i) {
            int c = h * 32 + ((i + row) & 31);
            unsigned long long cv = cand[row * 64 + c];
            best = cv < best ? cv : best;
        }
        unsigned lo = (unsigned)best, hw = (unsigned)(best >> 32);
        unsigned lo2 = __shfl_xor(lo, 1), hw2 = __shfl_xor(hw, 1);
        unsigned long long ob = (((unsigned long long)hw2) << 32) | lo2;
        if (ob < best) best = ob;
        if (h == 0) atomicMin(mp + n_blk + row, best);
    }
}

// ---------- unpack codes ----------
__global__ __launch_bounds__(256)
void codes_kernel(const unsigned long long* __restrict__ mp,
                  float* __restrict__ codes)
{
    int n = blockIdx.x * 256 + threadIdx.x;
    if (n < 8192) codes[n] = (float)(unsigned)(mp[n] & 0xffffffffULL);
}

// ---------------------------------------------------------------
extern "C" void kernel_launch(void* const* d_in, const int* in_sizes, int n_in,
                              void* d_out, int out_size, void* d_ws, size_t ws_size,
                              hipStream_t stream)
{
    const float* x   = (const float*)d_in[0];
    const float* w1  = (const float*)d_in[1];
    const float* b1  = (const float*)d_in[2];
    const float* w2  = (const float*)d_in[3];
    const float* b2  = (const float*)d_in[4];
    const float* w3  = (const float*)d_in[5];
    const float* b3  = (const float*)d_in[6];
    const float* w4  = (const float*)d_in[7];
    const float* b4  = (const float*)d_in[8];
    const float* g1  = (const float*)d_in[9];
    const float* be1 = (const float*)d_in[10];
    const float* m1  = (const float*)d_in[11];
    const float* v1  = (const float*)d_in[12];
    const float* g2  = (const float*)d_in[13];
    const float* be2 = (const float*)d_in[14];
    const float* m2  = (const float*)d_in[15];
    const float* v2  = (const float*)d_in[16];
    const float* g3  = (const float*)d_in[17];
    const float* be3 = (const float*)d_in[18];
    const float* m3  = (const float*)d_in[19];
    const float* v3  = (const float*)d_in[20];
    const float* g4  = (const float*)d_in[21];
    const float* be4 = (const float*)d_in[22];
    const float* m4  = (const float*)d_in[23];
    const float* v4  = (const float*)d_in[24];
    const float* emb = (const float*)d_in[25];

    float* outf  = (float*)d_out;
    float* codes = outf;
    float* distm = outf + 8192;

    // ---- workspace layout (bytes)
    char* wsb = (char*)d_ws;
    short* wb1 = (short*)(wsb + 0);
    short* wb2 = (short*)(wsb + 786432);
    short* wb3 = (short*)(wsb + 2359296);
    short* wb4 = (short*)(wsb + 5505024);
    float* sc1 = (float*)(wsb + 6291456); float* off1 = sc1 + 256;
    float* sc2 = (float*)(wsb + 6293504); float* off2 = sc2 + 512;
    float* sc3 = (float*)(wsb + 6297600); float* off3 = sc3 + 512;
    float* sc4 = (float*)(wsb + 6301696); float* off4 = sc4 + 128;
    short* h1p = (short*)(wsb + 6302720);        // 33,619,968
    short* fh  = (short*)(wsb + 39922688);       // 2,097,152 each
    short* fl  = (short*)(wsb + 42019840);
    short* eh  = (short*)(wsb + 44116992);       // 1,048,576 each
    short* el  = (short*)(wsb + 45165568);
    float* sf  = (float*)(wsb + 46214144);       // 32,768
    float* se  = (float*)(wsb + 46246912);       // 16,384
    unsigned long long* mp = (unsigned long long*)(wsb + 46263296);  // 65,536

    // ---- large scratch in the (dead-until-dist) dist region of d_out
    char* db = (char*)distm;
    short* xpl = (short*)db;                      // L1 input planes
    short* h2p = (short*)db;                      // L2 output planes
    short* h3p = (short*)(db + 33685504);         // L3 output planes

    // ---- prep
    wprep_all<<<dim3(192, 4), 256, 0, stream>>>(w1, wb1, w2, wb2, w3, wb3, w4, wb4);
    bnprep_init<<<70, 256, 0, stream>>>(
        g1, be1, m1, v1, b1, sc1, off1,
        g2, be2, m2, v2, b2, sc2, off2,
        g3, be3, m3, v3, b3, sc3, off3,
        g4, be4, m4, v4, b4, sc4, off4, mp, sf);
    split_kernel<<<256, 256, 0, stream>>>(emb, 4096, eh, el, se);

    // ---- input split + conv stack
    xsplit<<<dim3(8, 32, 32), 256, 0, stream>>>(x, xpl);
    conv_pair<256, 256, 2048, 128, 0>
        <<<dim3(8, 1, 32), 512, 0, stream>>>(wb1, xpl, sc1, off1, h1p);
    conv_pair<256, 512, 1024, 128, 0>
        <<<dim3(4, 2, 32), 512, 0, stream>>>(wb2, h1p, sc2, off2, h2p);
    conv_pair<512, 512, 512, 64, 1>
        <<<dim3(4, 2, 32), 512, 0, stream>>>(wb3, h2p, sc3, off3, h3p);
    conv_s1<512, 128, 256>
        <<<dim3(2, 1, 32), 256, 0, stream>>>(wb4, h3p, sc4, off4, fh, fl, sf);

    // ---- VQ: MFMA distance + fused argmin, unpack codes
    distmin_kernel<<<dim3(32, 64), 256, 0, stream>>>(fh, fl, eh, el,
                                                     sf, se, distm, mp);
    codes_kernel<<<32, 256, 0, stream>>>(mp, codes);
}

// Round 11
// 235.065 us; speedup vs baseline: 1.1224x; 1.1120x over previous
//
#include <hip/hip_runtime.h>
#include <cstdint>
#include <math.h>

#define EPS_BN 1e-5f
#define SLOPE 0.01f
#define C14 6.103515625e-5f     // 2^-14 combine factor
#define SC14 16384.0f           // 2^14 residual scale
#define HMIN 6.103515625e-5f    // fp16 min normal

typedef __attribute__((ext_vector_type(8))) _Float16 half8;
typedef __attribute__((ext_vector_type(8))) short short8;
typedef __attribute__((ext_vector_type(16))) float f32x16;
typedef __attribute__((ext_vector_type(4))) float f32x4;

// 2-way fp16 split: v = h + 2^-14 * l
__device__ __forceinline__ void split16(float v, unsigned short& uh,
                                        unsigned short& ul) {
    _Float16 h = (_Float16)v;
    if (fabsf(v) < HMIN) h = (_Float16)0.0f;
    float rem = v - (float)h;
    _Float16 l = (_Float16)(rem * SC14);
    uh = __builtin_bit_cast(unsigned short, h);
    ul = __builtin_bit_cast(unsigned short, l);
}

// ---------- weight prep, ALL layers ----------
__global__ __launch_bounds__(256)
void wprep_all(const float* __restrict__ w1, short* __restrict__ o1,
               const float* __restrict__ w2, short* __restrict__ o2,
               const float* __restrict__ w3, short* __restrict__ o3,
               const float* __restrict__ w4, short* __restrict__ o4)
{
    const float* w; short* wbuf; int CIN, COUT;
    switch (blockIdx.y) {
        case 0: w = w1; wbuf = o1; CIN = 256; COUT = 256; break;
        case 1: w = w2; wbuf = o2; CIN = 256; COUT = 512; break;
        case 2: w = w3; wbuf = o3; CIN = 512; COUT = 512; break;
        default: w = w4; wbuf = o4; CIN = 512; COUT = 128; break;
    }
    int KST = CIN / 16, OB = COUT / 128;
    int total = KST * OB * 1536;
    for (int sid = blockIdx.x * 256 + threadIdx.x; sid < total;
         sid += gridDim.x * 256) {
        int slot = sid % 1536;
        int kb = sid / 1536;
        int ob = kb % OB, ks = kb / OB;
        int m = slot & 31, hi = (slot >> 5) & 1, mf = (slot >> 6) & 3;
        int ts = slot >> 8;
        int t = ts >> 1, s = ts & 1;
        int oc = ob * 128 + mf * 32 + m;
        int ib = ks * 16 + hi * 8;
        short8 r;
        #pragma unroll
        for (int j = 0; j < 8; ++j) {
            float v = w[((size_t)oc * CIN + ib + j) * 3 + t];
            unsigned short uh, ul;
            split16(v, uh, ul);
            r[j] = (short)(s == 0 ? uh : ul);
        }
        *(short8*)(wbuf + (size_t)sid * 8) = r;
    }
}

// ---------- BN affine prep + mp init + sf zero ----------
__global__ __launch_bounds__(256)
void bnprep_init(
    const float* __restrict__ g1, const float* __restrict__ be1,
    const float* __restrict__ m1, const float* __restrict__ v1,
    const float* __restrict__ b1, float* __restrict__ sc1, float* __restrict__ off1,
    const float* __restrict__ g2, const float* __restrict__ be2,
    const float* __restrict__ m2, const float* __restrict__ v2,
    const float* __restrict__ b2, float* __restrict__ sc2, float* __restrict__ off2,
    const float* __restrict__ g3, const float* __restrict__ be3,
    const float* __restrict__ m3, const float* __restrict__ v3,
    const float* __restrict__ b3, float* __restrict__ sc3, float* __restrict__ off3,
    const float* __restrict__ g4, const float* __restrict__ be4,
    const float* __restrict__ m4, const float* __restrict__ v4,
    const float* __restrict__ b4, float* __restrict__ sc4, float* __restrict__ off4,
    unsigned long long* __restrict__ mp, float* __restrict__ sf)
{
    int bid = blockIdx.x;
    if (bid >= 38) { sf[(bid - 38) * 256 + threadIdx.x] = 0.0f; return; }
    if (bid >= 6) { mp[(bid - 6) * 256 + threadIdx.x] = ~0ULL; return; }
    const float *g, *be, *m, *v, *bias;
    float *sc, *off;
    int c;
    if (bid == 0) {
        g = g1; be = be1; m = m1; v = v1; bias = b1; sc = sc1; off = off1;
        c = threadIdx.x;
    } else if (bid <= 2) {
        g = g2; be = be2; m = m2; v = v2; bias = b2; sc = sc2; off = off2;
        c = (bid - 1) * 256 + threadIdx.x;
    } else if (bid <= 4) {
        g = g3; be = be3; m = m3; v = v3; bias = b3; sc = sc3; off = off3;
        c = (bid - 3) * 256 + threadIdx.x;
    } else {
        g = g4; be = be4; m = m4; v = v4; bias = b4; sc = sc4; off = off4;
        c = threadIdx.x;
        if (c >= 128) return;
    }
    float s = g[c] / sqrtf(v[c] + EPS_BN);
    sc[c] = s;
    off[c] = (bias[c] - m[c]) * s + be[c];
}

// ---------- paired-OC conv (stride 2), reg-staged single-barrier pipeline ----
// SRC=0: input = pre-split fp16 planes. SRC=1: input = raw fp32 x (split
// in-kernel; replaces the xsplit pass). 512 thr / 8 waves; 256 oc x TILE pos.
// Loop: load(ks+1)->regs ; MFMA(buf[ks&1]) ; ds_write regs->buf[ks&1^1] ; bar.
template<int CIN, int COUT, int LIN, int TILE, int EPI, int SRC>
__global__ __launch_bounds__(512, 1)
void conv_pair(const short* __restrict__ wbuf, const short* __restrict__ xpl,
               const float* __restrict__ xraw,
               const float* __restrict__ scv, const float* __restrict__ offv,
               short* __restrict__ opl)
{
    constexpr int LOUT = LIN / 2;
    constexpr int KST = CIN / 16;
    constexpr int OBS = COUT / 128;
    constexpr int NG = CIN / 8;
    constexpr int SLOTS = LIN / 2 + 1;
    constexpr size_t PLIN = (size_t)32 * NG * 2 * SLOTS * 8;
    constexpr int NF = TILE / 64;
    constexpr int NGo = COUT / 8;
    constexpr int OSLOTS = (EPI == 0) ? (LOUT / 2 + 1) : (LOUT + 2);
    constexpr size_t PLOUT = (size_t)32 * NGo * ((EPI == 0) ? 2 : 1) * OSLOTS * 8;

    constexpr int XOFF = 49152;              // W: [0,49152) per buffer
    constexpr int BUF  = XOFF + 8 * 2112;    // 66048 per buffer
    constexpr int SCOFF = 2 * BUF;           // 132096
    __shared__ __align__(16) char lds[2 * BUF + 2048];

    const int tid = threadIdx.x;
    const int lane = tid & 63;
    const int wv = tid >> 6;
    const int wo = wv >> 2;
    const int wm = (wv >> 1) & 1, wn = wv & 1;
    const int hi = lane >> 5, n32 = lane & 31;
    const int n0 = blockIdx.x * TILE;
    const int oby = blockIdx.y;
    const int o0 = oby * 256;
    const int b = blockIdx.z;

    if (tid < 256) ((float*)(lds + SCOFF))[tid] = scv[o0 + tid];
    else ((float*)(lds + SCOFF + 1024))[tid - 256] = offv[o0 + tid - 256];

    f32x16 acc0[2][2], acc1[2][2];
    #pragma unroll
    for (int i = 0; i < 2; ++i)
        #pragma unroll
        for (int j = 0; j < 2; ++j)
            #pragma unroll
            for (int e = 0; e < 16; ++e) { acc0[i][j][e] = 0.0f; acc1[i][j][e] = 0.0f; }

    // staging registers
    short8 rw[6];
    short8 rxa, rxb, rxc;            // SRC==0
    float rf[8], rf2[8];             // SRC==1

    auto stage_load = [&](int ks) {
        const short* wsrc = wbuf + ((size_t)ks * OBS + (oby * 2 + wo)) * 1536 * 8;
        #pragma unroll
        for (int it = 0; it < 6; ++it)
            rw[it] = *(const short8*)(wsrc +
                      (size_t)(it * 256 + (wv & 3) * 64 + lane) * 8);
        if constexpr (SRC == 0) {
            int sg = wv >> 2, rhi = (wv >> 1) & 1, arr = wv & 1;
            int start = arr ? n0 : (n0 + 1);
            const short* src = xpl + (size_t)sg * PLIN
                + ((((size_t)b * NG + (ks * 2 + rhi)) * 2 + arr) * SLOTS + start) * 8;
            rxa = *(const short8*)(src + (size_t)lane * 8);
            if constexpr (TILE == 128) {
                rxb = *(const short8*)(src + (size_t)(64 + lane) * 8);
                if (arr && lane == 0)
                    rxc = *(const short8*)(src + (size_t)128 * 8);
            } else {
                if (arr && lane == 0)
                    rxb = *(const short8*)(src + (size_t)64 * 8);
            }
        } else {
            int run = wv & 3, rhi = run >> 1, arr = run & 1, hs = wv >> 2;
            int c = hs * 64 + lane;
            int l = arr ? (2 * (n0 + c) - 1) : (2 * (n0 + c));
            const float* xr = xraw + ((size_t)(b * 256 + ks * 16 + rhi * 8)) * 2048;
            #pragma unroll
            for (int j = 0; j < 8; ++j)
                rf[j] = (l >= 0) ? xr[(size_t)j * 2048 + l] : 0.0f;
            if (arr && hs == 1 && lane == 0) {
                int l2 = 2 * (n0 + 128) - 1;
                #pragma unroll
                for (int j = 0; j < 8; ++j)
                    rf2[j] = xr[(size_t)j * 2048 + l2];
            }
        }
    };

    auto stage_write = [&](char* base) {
        #pragma unroll
        for (int it = 0; it < 6; ++it)
            *(short8*)(base + wo * 24576 +
                       (it * 256 + (wv & 3) * 64 + lane) * 16) = rw[it];
        if constexpr (SRC == 0) {
            int sg = wv >> 2, rhi = (wv >> 1) & 1, arr = wv & 1;
            char* dst = base + XOFF + ((sg * 2 + rhi) * 2 + arr) * 2112;
            *(short8*)(dst + lane * 16) = rxa;
            if constexpr (TILE == 128) {
                *(short8*)(dst + (64 + lane) * 16) = rxb;
                if (arr && lane == 0) *(short8*)(dst + 128 * 16) = rxc;
            } else {
                if (arr && lane == 0) *(short8*)(dst + 64 * 16) = rxb;
            }
        } else {
            int run = wv & 3, rhi = run >> 1, arr = run & 1, hs = wv >> 2;
            int c = hs * 64 + lane;
            short8 rh, rl;
            #pragma unroll
            for (int j = 0; j < 8; ++j) {
                unsigned short uh, ul;
                split16(rf[j], uh, ul);
                rh[j] = (short)uh; rl[j] = (short)ul;
            }
            char* dst = base + XOFF + (rhi * 2 + arr) * 2112;
            *(short8*)(dst + c * 16) = rh;
            *(short8*)(dst + 8448 + c * 16) = rl;
            if (arr && hs == 1 && lane == 0) {
                short8 rh2, rl2;
                #pragma unroll
                for (int j = 0; j < 8; ++j) {
                    unsigned short uh, ul;
                    split16(rf2[j], uh, ul);
                    rh2[j] = (short)uh; rl2[j] = (short)ul;
                }
                *(short8*)(dst + 128 * 16) = rh2;
                *(short8*)(dst + 8448 + 128 * 16) = rl2;
            }
        }
    };

    stage_load(0);
    stage_write(lds);
    __syncthreads();

    #pragma unroll 1
    for (int ks = 0; ks < KST; ++ks) {
        const char* cbase = lds + (ks & 1) * BUF;
        bool more = (ks + 1 < KST);
        if (more) stage_load(ks + 1);           // loads in flight under MFMA
        __builtin_amdgcn_s_setprio(1);
        #pragma unroll
        for (int t = 0; t < 3; ++t) {
            half8 af[2][2], bx[2][2];
            #pragma unroll
            for (int s = 0; s < 2; ++s) {
                #pragma unroll
                for (int mf = 0; mf < 2; ++mf)
                    af[s][mf] = *(const half8*)(cbase + wo * 24576 +
                        (((t * 2 + s) * 4 + (wm * 2 + mf)) * 64 + lane) * 16);
                int arr = (t == 1) ? 0 : 1;
                int tof = (t == 2) ? 1 : 0;
                #pragma unroll
                for (int nf = 0; nf < NF; ++nf) {
                    int qb = wn * (TILE / 2) + nf * 32 + tof;
                    bx[s][nf] = *(const half8*)(cbase + XOFF + s * 8448
                                                + arr * 2112 + qb * 16
                                                + hi * 4224 + n32 * 16);
                }
            }
            #pragma unroll
            for (int mf = 0; mf < 2; ++mf)
                #pragma unroll
                for (int nf = 0; nf < NF; ++nf) {
                    acc0[mf][nf] = __builtin_amdgcn_mfma_f32_32x32x16_f16(
                        af[0][mf], bx[0][nf], acc0[mf][nf], 0, 0, 0);
                    acc1[mf][nf] = __builtin_amdgcn_mfma_f32_32x32x16_f16(
                        af[0][mf], bx[1][nf], acc1[mf][nf], 0, 0, 0);
                    acc1[mf][nf] = __builtin_amdgcn_mfma_f32_32x32x16_f16(
                        af[1][mf], bx[0][nf], acc1[mf][nf], 0, 0, 0);
                }
        }
        __builtin_amdgcn_s_setprio(0);
        if (more) stage_write(lds + ((ks + 1) & 1) * BUF);
        __syncthreads();                         // one barrier per step
    }

    // ---- epilogue ----
    #pragma unroll
    for (int half = 0; half < NF; ++half) {
        __syncthreads();
        #pragma unroll
        for (int mf = 0; mf < 2; ++mf)
            #pragma unroll
            for (int r = 0; r < 16; ++r) {
                int ocl = mf * 32 + (r & 3) + 8 * (r >> 2) + 4 * hi;
                *(float*)(lds + wv * 8704 + n32 * 272 + ocl * 4) =
                    acc0[mf][half][r] + C14 * acc1[mf][half][r];
            }
        __syncthreads();
        #pragma unroll
        for (int it = 0; it < 4; ++it) {
            int sl = tid + it * 512;
            int w = sl >> 8, rem = sl & 255, p = rem >> 3, grp = rem & 7;
            int wo_ = w >> 2, wm_ = (w >> 1) & 1, wn_ = w & 1;
            f32x4 v0 = *(f32x4*)(lds + w * 8704 + p * 272 + grp * 32);
            f32x4 v1 = *(f32x4*)(lds + w * 8704 + p * 272 + grp * 32 + 16);
            int ocb = wo_ * 128 + wm_ * 64 + grp * 8;
            f32x4 s0 = *(f32x4*)(lds + SCOFF + ocb * 4);
            f32x4 s1 = *(f32x4*)(lds + SCOFF + ocb * 4 + 16);
            f32x4 q0 = *(f32x4*)(lds + SCOFF + 1024 + ocb * 4);
            f32x4 q1 = *(f32x4*)(lds + SCOFF + 1024 + ocb * 4 + 16);
            float y[8];
            #pragma unroll
            for (int j = 0; j < 4; ++j) {
                float a = v0[j] * s0[j] + q0[j];
                y[j] = a >= 0.0f ? a : SLOPE * a;
                float c = v1[j] * s1[j] + q1[j];
                y[4 + j] = c >= 0.0f ? c : SLOPE * c;
            }
            int pos_abs = n0 + wn_ * (TILE / 2) + half * 32 + p;
            int oc_abs = o0 + ocb;
            short8 rh, rl;
            #pragma unroll
            for (int j = 0; j < 8; ++j) {
                unsigned short uh, ul;
                split16(y[j], uh, ul);
                rh[j] = (short)uh; rl[j] = (short)ul;
            }
            int gq = oc_abs >> 3;
            size_t base;
            if (EPI == 0) {
                int arr = pos_abs & 1;
                int slot = arr ? (pos_abs + 1) / 2 : pos_abs / 2 + 1;
                base = ((((size_t)b * NGo + gq) * 2 + arr) * OSLOTS + slot) * 8;
            } else {
                base = (((size_t)b * NGo + gq) * OSLOTS + (pos_abs + 1)) * 8;
            }
            *(short8*)(opl + base) = rh;
            *(short8*)(opl + PLOUT + base) = rl;
        }
    }

    if (EPI == 0) {
        if (blockIdx.x == 0 && tid < 128) {
            int sg = tid >> 6, r2 = tid & 63, g16 = r2 >> 1, a2 = r2 & 1;
            int gq = oby * 32 + g16;
            short8 z;
            #pragma unroll
            for (int j = 0; j < 8; ++j) z[j] = 0;
            *(short8*)(opl + (size_t)sg * PLOUT +
                       ((((size_t)b * NGo + gq) * 2 + a2) * OSLOTS) * 8) = z;
        }
    } else {
        if (tid < 64 && (blockIdx.x == 0 || blockIdx.x == gridDim.x - 1)) {
            int sg = tid >> 5, g16 = tid & 31;
            int gq = oby * 32 + g16;
            int slot = (blockIdx.x == 0) ? 0 : (OSLOTS - 1);
            short8 z;
            #pragma unroll
            for (int j = 0; j < 8; ++j) z[j] = 0;
            *(short8*)(opl + (size_t)sg * PLOUT +
                       (((size_t)b * NGo + gq) * OSLOTS + slot) * 8) = z;
        }
    }
}

// ---------- stride-1 conv (layer 4), reg-staged, TILE=64 (128 blocks) ----------
// Fused: BN+LReLU + direct fp16-split feature planes + sumsq (atomicAdd).
template<int CIN, int COUT, int LIN>
__global__ __launch_bounds__(256, 2)
void conv_s1(const short* __restrict__ wbuf, const short* __restrict__ xpl,
             const float* __restrict__ scv, const float* __restrict__ offv,
             short* __restrict__ fh, short* __restrict__ fl,
             float* __restrict__ sf)
{
    constexpr int KST = CIN / 16;
    constexpr int NG = CIN / 8;
    constexpr int SLOTS = LIN + 2;
    constexpr size_t PLIN = (size_t)32 * NG * SLOTS * 8;
    constexpr int TILE = 64;

    constexpr int XOFF = 24576;
    constexpr int BUF  = XOFF + 4 * 2112;    // 33024
    constexpr int SCOFF = 2 * BUF;           // 66048
    __shared__ __align__(16) char lds[2 * BUF + 1024];

    const int tid = threadIdx.x;
    const int lane = tid & 63;
    const int wv = tid >> 6;
    const int wm = wv >> 1, wn = wv & 1;
    const int hi = lane >> 5, n32 = lane & 31;
    const int n0 = blockIdx.x * TILE;
    const int b = blockIdx.z;

    if (tid < 128) {
        ((float*)(lds + SCOFF))[tid] = scv[tid];
        ((float*)(lds + SCOFF + 512))[tid] = offv[tid];
    }

    f32x16 acc0[2], acc1[2];
    #pragma unroll
    for (int i = 0; i < 2; ++i)
        #pragma unroll
        for (int e = 0; e < 16; ++e) { acc0[i][e] = 0.0f; acc1[i][e] = 0.0f; }

    short8 rw[6], rxa, rxb;

    auto stage_load = [&](int ks) {
        const short* wsrc = wbuf + (size_t)ks * 1536 * 8;
        #pragma unroll
        for (int it = 0; it < 6; ++it)
            rw[it] = *(const short8*)(wsrc +
                      (size_t)(it * 256 + wv * 64 + lane) * 8);
        int sg = wv >> 1, rhi = wv & 1;
        const short* src = xpl + (size_t)sg * PLIN
            + (((size_t)b * NG + (ks * 2 + rhi)) * SLOTS + n0) * 8;
        rxa = *(const short8*)(src + (size_t)lane * 8);
        if (lane < 2) rxb = *(const short8*)(src + (size_t)(64 + lane) * 8);
    };
    auto stage_write = [&](char* base) {
        #pragma unroll
        for (int it = 0; it < 6; ++it)
            *(short8*)(base + (it * 256 + wv * 64 + lane) * 16) = rw[it];
        int sg = wv >> 1, rhi = wv & 1;
        char* dst = base + XOFF + (sg * 2 + rhi) * 2112;
        *(short8*)(dst + lane * 16) = rxa;
        if (lane < 2) *(short8*)(dst + (64 + lane) * 16) = rxb;
    };

    stage_load(0);
    stage_write(lds);
    __syncthreads();

    #pragma unroll 1
    for (int ks = 0; ks < KST; ++ks) {
        const char* cbase = lds + (ks & 1) * BUF;
        bool more = (ks + 1 < KST);
        if (more) stage_load(ks + 1);
        __builtin_amdgcn_s_setprio(1);
        #pragma unroll
        for (int t = 0; t < 3; ++t) {
            half8 af[2][2], bx[2];
            #pragma unroll
            for (int s = 0; s < 2; ++s) {
                #pragma unroll
                for (int mf = 0; mf < 2; ++mf)
                    af[s][mf] = *(const half8*)(cbase +
                        (((t * 2 + s) * 4 + (wm * 2 + mf)) * 64 + lane) * 16);
                int qb = wn * 32 + t;
                bx[s] = *(const half8*)(cbase + XOFF + s * 4224
                                        + qb * 16 + hi * 2112 + n32 * 16);
            }
            #pragma unroll
            for (int mf = 0; mf < 2; ++mf) {
                acc0[mf] = __builtin_amdgcn_mfma_f32_32x32x16_f16(
                    af[0][mf], bx[0], acc0[mf], 0, 0, 0);
                acc1[mf] = __builtin_amdgcn_mfma_f32_32x32x16_f16(
                    af[0][mf], bx[1], acc1[mf], 0, 0, 0);
                acc1[mf] = __builtin_amdgcn_mfma_f32_32x32x16_f16(
                    af[1][mf], bx[0], acc1[mf], 0, 0, 0);
            }
        }
        __builtin_amdgcn_s_setprio(0);
        if (more) stage_write(lds + ((ks + 1) & 1) * BUF);
        __syncthreads();
    }

    // ---- epilogue: combine + affine + lrelu + split planes + sumsq ----
    __syncthreads();
    #pragma unroll
    for (int mf = 0; mf < 2; ++mf)
        #pragma unroll
        for (int r = 0; r < 16; ++r) {
            int ocl = mf * 32 + (r & 3) + 8 * (r >> 2) + 4 * hi;
            *(float*)(lds + wv * 8704 + n32 * 272 + ocl * 4) =
                acc0[mf][r] + C14 * acc1[mf][r];
        }
    __syncthreads();
    #pragma unroll
    for (int it = 0; it < 4; ++it) {
        int sl = tid + it * 256;
        int w = sl >> 8, rem = sl & 255, p = rem >> 3, grp = rem & 7;
        int wm_ = w >> 1, wn_ = w & 1;
        f32x4 v0 = *(f32x4*)(lds + w * 8704 + p * 272 + grp * 32);
        f32x4 v1 = *(f32x4*)(lds + w * 8704 + p * 272 + grp * 32 + 16);
        int oclb = wm_ * 64 + grp * 8;
        f32x4 s0 = *(f32x4*)(lds + SCOFF + oclb * 4);
        f32x4 s1 = *(f32x4*)(lds + SCOFF + oclb * 4 + 16);
        f32x4 q0 = *(f32x4*)(lds + SCOFF + 512 + oclb * 4);
        f32x4 q1 = *(f32x4*)(lds + SCOFF + 512 + oclb * 4 + 16);
        float y[8];
        #pragma unroll
        for (int j = 0; j < 4; ++j) {
            float a = v0[j] * s0[j] + q0[j];
            y[j] = a >= 0.0f ? a : SLOPE * a;
            float c = v1[j] * s1[j] + q1[j];
            y[4 + j] = c >= 0.0f ? c : SLOPE * c;
        }
        int pos_abs = n0 + wn_ * 32 + p;
        int n = b * 256 + pos_abs;
        short8 rh, rl;
        float partial = 0.0f;
        #pragma unroll
        for (int j = 0; j < 8; ++j) {
            partial = fmaf(y[j], y[j], partial);
            unsigned short uh, ul;
            split16(y[j], uh, ul);
            rh[j] = (short)uh; rl[j] = (short)ul;
        }
        int g = wm_ * 8 + grp;
        size_t slot = ((((size_t)(n >> 5) * 8 + (g >> 1)) * 2 + (g & 1)) * 32
                       + (n & 31)) * 8;
        *(short8*)(fh + slot) = rh;
        *(short8*)(fl + slot) = rl;
        atomicAdd(sf + n, partial);
    }
}

// ---------- row split (emb only): fp32 -> 2 fp16 planes + sumsq ----------
__global__ __launch_bounds__(256)
void split_kernel(const float* __restrict__ src, int nrows,
                  short* __restrict__ ph, short* __restrict__ pl,
                  float* __restrict__ sumv)
{
    int t = blockIdx.x * 256 + threadIdx.x;
    int n = t >> 4, g = t & 15;
    if (n >= nrows) return;
    const float* rowp = src + (size_t)n * 128 + g * 8;
    float4 v0 = *(const float4*)rowp;
    float4 v1 = *(const float4*)(rowp + 4);
    float vv[8] = {v0.x, v0.y, v0.z, v0.w, v1.x, v1.y, v1.z, v1.w};
    short8 rh, rl;
    float ss = 0.0f;
    #pragma unroll
    for (int j = 0; j < 8; ++j) {
        float v = vv[j];
        ss = fmaf(v, v, ss);
        unsigned short uh, ul;
        split16(v, uh, ul);
        rh[j] = (short)uh; rl[j] = (short)ul;
    }
    int nb = n >> 5, m = n & 31, ks = g >> 1, hi = g & 1;
    size_t slot = ((((size_t)nb * 8 + ks) * 2 + hi) * 32 + m) * 8;
    *(short8*)(ph + slot) = rh;
    *(short8*)(pl + slot) = rl;
    #pragma unroll
    for (int mk = 8; mk; mk >>= 1) ss += __shfl_xor(ss, mk);
    if (g == 0) sumv[n] = ss;
}

// ---------- dist tile (128n x 128k): direct-from-global fp16-split MFMA + argmin
__global__ __launch_bounds__(256, 2)
void distmin_kernel(const short* __restrict__ fh, const short* __restrict__ fl,
                    const short* __restrict__ eh, const short* __restrict__ el,
                    const float* __restrict__ sf, const float* __restrict__ se,
                    float* __restrict__ dist, unsigned long long* __restrict__ mp)
{
    __shared__ unsigned long long cand[128 * 64];   // 64 KB
    const int tid = threadIdx.x;
    const int lane = tid & 63;
    const int wv = tid >> 6;
    const int wm = wv >> 1, wn = wv & 1;
    const int hi = lane >> 5, n32 = lane & 31;
    const int kb = blockIdx.x;
    const int nb = blockIdx.y;

    f32x16 acc0[2][2], acc1[2][2];
    #pragma unroll
    for (int i = 0; i < 2; ++i)
        #pragma unroll
        for (int j = 0; j < 2; ++j)
            #pragma unroll
            for (int e = 0; e < 16; ++e) { acc0[i][j][e] = 0.0f; acc1[i][j][e] = 0.0f; }

    const short* fb[2][2];
    const short* eb[2][2];
    {
        const short* fpl[2] = {fh, fl};
        const short* epl[2] = {eh, el};
        #pragma unroll
        for (int s = 0; s < 2; ++s) {
            #pragma unroll
            for (int mf = 0; mf < 2; ++mf)
                fb[s][mf] = fpl[s] + (size_t)nb * 16384
                            + ((size_t)(wm * 2 + mf) * 8 * 64 + lane) * 8;
            #pragma unroll
            for (int nf = 0; nf < 2; ++nf)
                eb[s][nf] = epl[s]
                            + ((size_t)(kb * 4 + wn * 2 + nf) * 8 * 64 + lane) * 8;
        }
    }

    #pragma unroll
    for (int ks = 0; ks < 8; ++ks) {
        half8 af[2][2], bx[2][2];
        #pragma unroll
        for (int s = 0; s < 2; ++s) {
            #pragma unroll
            for (int mf = 0; mf < 2; ++mf)
                af[s][mf] = *(const half8*)(fb[s][mf] + ks * 512);
            #pragma unroll
            for (int nf = 0; nf < 2; ++nf)
                bx[s][nf] = *(const half8*)(eb[s][nf] + ks * 512);
        }
        #pragma unroll
        for (int mf = 0; mf < 2; ++mf)
            #pragma unroll
            for (int nf = 0; nf < 2; ++nf) {
                acc0[mf][nf] = __builtin_amdgcn_mfma_f32_32x32x16_f16(
                    af[0][mf], bx[0][nf], acc0[mf][nf], 0, 0, 0);
                acc1[mf][nf] = __builtin_amdgcn_mfma_f32_32x32x16_f16(
                    af[0][mf], bx[1][nf], acc1[mf][nf], 0, 0, 0);
                acc1[mf][nf] = __builtin_amdgcn_mfma_f32_32x32x16_f16(
                    af[1][mf], bx[0][nf], acc1[mf][nf], 0, 0, 0);
            }
    }

    const int n_blk = nb * 128;
    const int kc0 = kb * 128 + wn * 64 + n32;
    const float se0 = se[kc0];
    const float se1 = se[kc0 + 32];
    #pragma unroll
    for (int mf = 0; mf < 2; ++mf) {
        #pragma unroll
        for (int r = 0; r < 16; ++r) {
            int nloc = wm * 64 + mf * 32 + (r & 3) + 8 * (r >> 2) + 4 * hi;
            int n = n_blk + nloc;
            float sfn = sf[n];
            float d0 = acc0[mf][0][r] + C14 * acc1[mf][0][r];
            float d1 = acc0[mf][1][r] + C14 * acc1[mf][1][r];
            float v0 = (sfn + se0) - 2.0f * d0;
            float v1 = (sfn + se1) - 2.0f * d1;
            __builtin_nontemporal_store(v0, &dist[(size_t)n * 4096 + kc0]);
            __builtin_nontemporal_store(v1, &dist[(size_t)n * 4096 + kc0 + 32]);
            unsigned long long p0 =
                (((unsigned long long)__float_as_uint(v0)) << 32) | (unsigned)kc0;
            unsigned long long p1 =
                (((unsigned long long)__float_as_uint(v1)) << 32) | (unsigned)(kc0 + 32);
            unsigned long long p = p1 < p0 ? p1 : p0;
            cand[nloc * 64 + wn * 32 + n32] = p;
        }
    }
    __syncthreads();
    {
        int row = tid >> 1, h = tid & 1;
        unsigned long long best = ~0ULL;
        #pragma unroll
        for (int i = 0; i < 32; ++i) {
            int c = h * 32 + ((i + row) & 31);
            unsigned long long cv = cand[row * 64 + c];
            best = cv < best ? cv : best;
        }
        unsigned lo = (unsigned)best, hw = (unsigned)(best >> 32);
        unsigned lo2 = __shfl_xor(lo, 1), hw2 = __shfl_xor(hw, 1);
        unsigned long long ob = (((unsigned long long)hw2) << 32) | lo2;
        if (ob < best) best = ob;
        if (h == 0) atomicMin(mp + n_blk + row, best);
    }
}

// ---------- unpack codes ----------
__global__ __launch_bounds__(256)
void codes_kernel(const unsigned long long* __restrict__ mp,
                  float* __restrict__ codes)
{
    int n = blockIdx.x * 256 + threadIdx.x;
    if (n < 8192) codes[n] = (float)(unsigned)(mp[n] & 0xffffffffULL);
}

// ---------------------------------------------------------------
extern "C" void kernel_launch(void* const* d_in, const int* in_sizes, int n_in,
                              void* d_out, int out_size, void* d_ws, size_t ws_size,
                              hipStream_t stream)
{
    const float* x   = (const float*)d_in[0];
    const float* w1  = (const float*)d_in[1];
    const float* b1  = (const float*)d_in[2];
    const float* w2  = (const float*)d_in[3];
    const float* b2  = (const float*)d_in[4];
    const float* w3  = (const float*)d_in[5];
    const float* b3  = (const float*)d_in[6];
    const float* w4  = (const float*)d_in[7];
    const float* b4  = (const float*)d_in[8];
    const float* g1  = (const float*)d_in[9];
    const float* be1 = (const float*)d_in[10];
    const float* m1  = (const float*)d_in[11];
    const float* v1  = (const float*)d_in[12];
    const float* g2  = (const float*)d_in[13];
    const float* be2 = (const float*)d_in[14];
    const float* m2  = (const float*)d_in[15];
    const float* v2  = (const float*)d_in[16];
    const float* g3  = (const float*)d_in[17];
    const float* be3 = (const float*)d_in[18];
    const float* m3  = (const float*)d_in[19];
    const float* v3  = (const float*)d_in[20];
    const float* g4  = (const float*)d_in[21];
    const float* be4 = (const float*)d_in[22];
    const float* m4  = (const float*)d_in[23];
    const float* v4  = (const float*)d_in[24];
    const float* emb = (const float*)d_in[25];

    float* outf  = (float*)d_out;
    float* codes = outf;
    float* distm = outf + 8192;

    // ---- workspace layout (bytes)
    char* wsb = (char*)d_ws;
    short* wb1 = (short*)(wsb + 0);
    short* wb2 = (short*)(wsb + 786432);
    short* wb3 = (short*)(wsb + 2359296);
    short* wb4 = (short*)(wsb + 5505024);
    float* sc1 = (float*)(wsb + 6291456); float* off1 = sc1 + 256;
    float* sc2 = (float*)(wsb + 6293504); float* off2 = sc2 + 512;
    float* sc3 = (float*)(wsb + 6297600); float* off3 = sc3 + 512;
    float* sc4 = (float*)(wsb + 6301696); float* off4 = sc4 + 128;
    short* h1p = (short*)(wsb + 6302720);        // 33,619,968
    short* fh  = (short*)(wsb + 39922688);       // 2,097,152 each
    short* fl  = (short*)(wsb + 42019840);
    short* eh  = (short*)(wsb + 44116992);       // 1,048,576 each
    short* el  = (short*)(wsb + 45165568);
    float* sf  = (float*)(wsb + 46214144);       // 32,768
    float* se  = (float*)(wsb + 46246912);       // 16,384
    unsigned long long* mp = (unsigned long long*)(wsb + 46263296);  // 65,536

    // ---- large scratch in the (dead-until-dist) dist region of d_out
    char* db = (char*)distm;
    short* h2p = (short*)db;                      // L2 output planes
    short* h3p = (short*)(db + 33685504);         // L3 output planes

    // ---- prep
    wprep_all<<<dim3(192, 4), 256, 0, stream>>>(w1, wb1, w2, wb2, w3, wb3, w4, wb4);
    bnprep_init<<<70, 256, 0, stream>>>(
        g1, be1, m1, v1, b1, sc1, off1,
        g2, be2, m2, v2, b2, sc2, off2,
        g3, be3, m3, v3, b3, sc3, off3,
        g4, be4, m4, v4, b4, sc4, off4, mp, sf);
    split_kernel<<<256, 256, 0, stream>>>(emb, 4096, eh, el, se);

    // ---- conv stack (L1 consumes raw x; xsplit pass eliminated)
    conv_pair<256, 256, 2048, 128, 0, 1>
        <<<dim3(8, 1, 32), 512, 0, stream>>>(wb1, nullptr, x, sc1, off1, h1p);
    conv_pair<256, 512, 1024, 128, 0, 0>
        <<<dim3(4, 2, 32), 512, 0, stream>>>(wb2, h1p, nullptr, sc2, off2, h2p);
    conv_pair<512, 512, 512, 64, 1, 0>
        <<<dim3(4, 2, 32), 512, 0, stream>>>(wb3, h2p, nullptr, sc3, off3, h3p);
    conv_s1<512, 128, 256>
        <<<dim3(4, 1, 32), 256, 0, stream>>>(wb4, h3p, sc4, off4, fh, fl, sf);

    // ---- VQ: MFMA distance + fused argmin, unpack codes
    distmin_kernel<<<dim3(32, 64), 256, 0, stream>>>(fh, fl, eh, el,
                                                     sf, se, distm, mp);
    codes_kernel<<<32, 256, 0, stream>>>(mp, codes);
}